// Round 6
// baseline (1431.930 us; speedup 1.0000x reference)
//
#include <hip/hip_runtime.h>
#include <hip/hip_bf16.h>
#include <cstdint>
#include <cstddef>

#define D 128

typedef __hip_bfloat16 bf16;
typedef __attribute__((ext_vector_type(8))) short short8v;   // 8 bf16 (4 VGPR)
typedef __attribute__((ext_vector_type(4))) float f32x4;     // MFMA 16x16 acc

// ---------- typed load/store helpers ----------
__device__ inline float ld1(const float* p) { return *p; }
__device__ inline float ld1(const bf16* p) { return __bfloat162float(*p); }
__device__ inline float2 ld2(const float* p) { return *(const float2*)p; }
__device__ inline float2 ld2(const bf16* p) {
  __hip_bfloat162 v = *(const __hip_bfloat162*)p;
  float2 r; r.x = __bfloat162float(v.x); r.y = __bfloat162float(v.y); return r;
}
__device__ inline void st2(float* p, float a, float b) {
  float2 v; v.x = a; v.y = b; *(float2*)p = v;
}
__device__ inline void st2(bf16* p, float a, float b) {
  __hip_bfloat162 v; v.x = __float2bfloat16(a); v.y = __float2bfloat16(b);
  *(__hip_bfloat162*)p = v;
}

// bf16 bit helpers (RNE)
__device__ inline short f2bf(float x) {
  uint32_t u = __builtin_bit_cast(uint32_t, x);
  uint32_t r = (u + 0x7FFFu + ((u >> 16) & 1u)) >> 16;
  return (short)(uint16_t)r;
}
__device__ inline float bf2f(short s) {
  uint32_t u = ((uint32_t)(uint16_t)s) << 16;
  return __builtin_bit_cast(float, u);
}

__device__ inline f32x4 mfma16(short8v a, short8v b, f32x4 c) {
  return __builtin_amdgcn_mfma_f32_16x16x32_bf16(a, b, c, 0, 0, 0);
}

// ---------- u[l,rel,side][k] = sum_j W[l,rel,k,j] * a[l,rel,j] ----------
__global__ void compute_u_kernel(const float* __restrict__ Wsrc, const float* __restrict__ Wdst,
                                 const float* __restrict__ asrc, const float* __restrict__ adst,
                                 float* __restrict__ u) {
  int lr = blockIdx.x;
  int side = blockIdx.y;
  int k = threadIdx.x;
  const float* W = (side == 0 ? Wsrc : Wdst) + ((size_t)lr * D + k) * D;
  const float* a = (side == 0 ? asrc : adst) + (size_t)lr * D;
  float s = 0.f;
  for (int j = 0; j < D; ++j) s += W[j] * a[j];
  u[((size_t)lr * 2 + side) * D + k] = s;
}

// ---------- W split: Wh/Wl bf16, transposed [col][k] ----------
__global__ void wsplit_kernel(const float* __restrict__ Wsrc,
                              short* __restrict__ WhT, short* __restrict__ WlT) {
  int lr = blockIdx.x;
  const float* W = Wsrc + (size_t)lr * D * D;
  short* wh = WhT + (size_t)lr * D * D;
  short* wl = WlT + (size_t)lr * D * D;
  for (int i = threadIdx.x; i < D * D; i += blockDim.x) {
    int k = i >> 7, c = i & 127;
    float w = W[i];
    short h = f2bf(w);
    short l = f2bf(w - bf2f(h));
    wh[c * D + k] = h;
    wl[c * D + k] = l;
  }
}

// ---------- CSR build ----------
__global__ void count_kernel(const int* __restrict__ dst, int* __restrict__ cnt, int E) {
  int i = blockIdx.x * blockDim.x + threadIdx.x;
  if (i < E) atomicAdd(&cnt[dst[i]], 1);
}

__global__ void count2_kernel(const int* __restrict__ csrc, const int* __restrict__ cdst,
                              int* __restrict__ cnt_bycon, int* __restrict__ cnt_byvar, int E) {
  int i = blockIdx.x * blockDim.x + threadIdx.x;
  if (i < E) {
    atomicAdd(&cnt_bycon[cdst[i]], 1);
    atomicAdd(&cnt_byvar[csrc[i]], 1);
  }
}

__global__ void bsum3_kernel(const int* __restrict__ c0, const int* __restrict__ c1,
                             const int* __restrict__ c2, int* __restrict__ bsums,
                             int n0, int n1, int n2, int pb0, int pb1, int pb2) {
  __shared__ int red[256];
  int y = blockIdx.y;
  const int* cnt = (y == 0) ? c0 : (y == 1) ? c1 : c2;
  int n  = (y == 0) ? n0 : (y == 1) ? n1 : n2;
  int pb = (y == 0) ? pb0 : (y == 1) ? pb1 : pb2;
  int b = blockIdx.x, t = threadIdx.x;
  int base = b * pb;
  if (base >= n) return;
  int end = base + pb; if (end > n) end = n;
  int s = 0;
  for (int i = base + t; i < end; i += 256) s += cnt[i];
  red[t] = s;
  __syncthreads();
  #pragma unroll
  for (int off = 128; off; off >>= 1) {
    if (t < off) red[t] += red[t + off];
    __syncthreads();
  }
  if (t == 0) bsums[y * 1024 + b] = red[0];
}

__global__ void bscan3_kernel(int* __restrict__ bsums,
                              int* __restrict__ t0, int* __restrict__ t1, int* __restrict__ t2) {
  __shared__ int sh[1024];
  int y = blockIdx.x, t = threadIdx.x;
  int* bs = bsums + y * 1024;
  int v = bs[t];
  sh[t] = v;
  __syncthreads();
  for (int off = 1; off < 1024; off <<= 1) {
    int u = (t >= off) ? sh[t - off] : 0;
    __syncthreads();
    sh[t] += u;
    __syncthreads();
  }
  bs[t] = sh[t] - v;
  if (t == 1023) {
    int* tot = (y == 0) ? t0 : (y == 1) ? t1 : t2;
    *tot = sh[1023];
  }
}

__global__ void scanfill3_kernel(const int* __restrict__ c0, const int* __restrict__ c1,
                                 const int* __restrict__ c2, const int* __restrict__ bsums,
                                 int* __restrict__ rp0, int* __restrict__ rp1, int* __restrict__ rp2,
                                 int* __restrict__ cu0, int* __restrict__ cu1, int* __restrict__ cu2,
                                 int n0, int n1, int n2, int pb0, int pb1, int pb2) {
  __shared__ int sh[256];
  int y = blockIdx.y;
  const int* cnt = (y == 0) ? c0 : (y == 1) ? c1 : c2;
  int* rowptr    = (y == 0) ? rp0 : (y == 1) ? rp1 : rp2;
  int* cursor    = (y == 0) ? cu0 : (y == 1) ? cu1 : cu2;
  int n  = (y == 0) ? n0 : (y == 1) ? n1 : n2;
  int pb = (y == 0) ? pb0 : (y == 1) ? pb1 : pb2;
  int b = blockIdx.x, t = threadIdx.x;
  int base = b * pb;
  if (base >= n) return;
  int end = base + pb; if (end > n) end = n;
  int run = bsums[y * 1024 + b];
  for (int tile = base; tile < end; tile += 256) {
    int i = tile + t;
    int c = (i < end) ? cnt[i] : 0;
    __syncthreads();
    sh[t] = c;
    __syncthreads();
    for (int off = 1; off < 256; off <<= 1) {
      int u = (t >= off) ? sh[t - off] : 0;
      __syncthreads();
      sh[t] += u;
      __syncthreads();
    }
    int excl = sh[t] - c;
    if (i < end) {
      rowptr[i] = run + excl;
      cursor[i] = run + excl;
    }
    run += sh[255];
  }
}

__global__ void fill_kernel(const int* __restrict__ dst, const int* __restrict__ src,
                            int* __restrict__ cursor, int* __restrict__ col, int E) {
  int i = blockIdx.x * blockDim.x + threadIdx.x;
  if (i < E) {
    int p = atomicAdd(&cursor[dst[i]], 1);
    col[p] = src[i];
  }
}

__global__ void fill2_kernel(const int* __restrict__ csrc, const int* __restrict__ cdst,
                             int* __restrict__ cur_bycon, int* __restrict__ cur_byvar,
                             int* __restrict__ col_bycon, int* __restrict__ col_byvar, int E) {
  int i = blockIdx.x * blockDim.x + threadIdx.x;
  if (i < E) {
    int s = csrc[i], d = cdst[i];
    int p = atomicAdd(&cur_bycon[d], 1);
    col_bycon[p] = s;
    int q = atomicAdd(&cur_byvar[s], 1);
    col_byvar[q] = d;
  }
}

// ---------- merged matvec bundles: var rows (4 dots) + con rows (2 dots) ----------
template<typename T>
__global__ void vec_all_kernel(const T* __restrict__ xv, const T* __restrict__ xc,
                               const float* __restrict__ uv0, const float* __restrict__ uv1,
                               const float* __restrict__ uv2, const float* __restrict__ uv3,
                               const float* __restrict__ uc0, const float* __restrict__ uc1,
                               float* __restrict__ es0, float* __restrict__ ed0,
                               float* __restrict__ es1, float* __restrict__ ed2,
                               float* __restrict__ es2, float* __restrict__ ed1,
                               int V, int C) {
  int gw = (int)(((size_t)blockIdx.x * blockDim.x + threadIdx.x) >> 6);
  int lane = threadIdx.x & 63;
  if (gw < V) {
    const T* xr = xv + (size_t)gw * D;
    float xa = ld1(&xr[lane]), xb = ld1(&xr[lane + 64]);
    float p0 = xa * uv0[lane] + xb * uv0[lane + 64];
    float p1 = xa * uv1[lane] + xb * uv1[lane + 64];
    float p2 = xa * uv2[lane] + xb * uv2[lane + 64];
    float p3 = xa * uv3[lane] + xb * uv3[lane + 64];
    #pragma unroll
    for (int off = 32; off; off >>= 1) {
      p0 += __shfl_xor(p0, off);
      p1 += __shfl_xor(p1, off);
      p2 += __shfl_xor(p2, off);
      p3 += __shfl_xor(p3, off);
    }
    if (lane == 0) { es0[gw] = p0; ed0[gw] = p1; es1[gw] = p2; ed2[gw] = p3; }
  } else if (gw < V + C) {
    int g = gw - V;
    const T* xr = xc + (size_t)g * D;
    float xa = ld1(&xr[lane]), xb = ld1(&xr[lane + 64]);
    float p0 = xa * uc0[lane] + xb * uc0[lane + 64];
    float p1 = xa * uc1[lane] + xb * uc1[lane + 64];
    #pragma unroll
    for (int off = 32; off; off >>= 1) {
      p0 += __shfl_xor(p0, off);
      p1 += __shfl_xor(p1, off);
    }
    if (lane == 0) { es2[g] = p0; ed1[g] = p1; }
  }
}

// ---------- MFMA matmul block (split-bf16, fp32-equivalent) ----------
__device__ __forceinline__ void mm_writeback(float* Cb, f32x4* acc, bf16* H, int row0, int nrows,
                                             int tid, int wv, int c15, int q) {
  int rbase = wv * 16 + q * 4;
  #pragma unroll
  for (int t = 0; t < 8; ++t) {
    int col = t * 16 + c15;
    Cb[(rbase + 0) * 132 + col] = acc[t][0];
    Cb[(rbase + 1) * 132 + col] = acc[t][1];
    Cb[(rbase + 2) * 132 + col] = acc[t][2];
    Cb[(rbase + 3) * 132 + col] = acc[t][3];
  }
  __syncthreads();
  for (int i = tid * 2; i < 64 * D; i += 512) {
    int r = i >> 7, c = i & 127;
    int gr = row0 + r;
    if (gr < nrows) st2(&H[(size_t)gr * D + c], Cb[r * 132 + c], Cb[r * 132 + c + 1]);
  }
}

template<typename Tin, bool DUAL>
__device__ __forceinline__ void mm_block(
    const Tin* __restrict__ X,
    const short* __restrict__ wh0, const short* __restrict__ wl0,
    const short* __restrict__ wh1, const short* __restrict__ wl1,
    bf16* __restrict__ H0, bf16* __restrict__ H1,
    int nrows, int row0, char* lds_raw) {
  short* Xh = (short*)lds_raw;
  short* Xl = Xh + 64 * 136;
  int tid = threadIdx.x;
  for (int i = tid * 4; i < 64 * D; i += 1024) {
    int r = i >> 7, c = i & 127;
    int gr = row0 + r; if (gr >= nrows) gr = nrows - 1;
    const Tin* src = X + (size_t)gr * D + c;
    float2 v01 = ld2(src), v23 = ld2(src + 2);
    int o = r * 136 + c;
    short h0 = f2bf(v01.x), h1 = f2bf(v01.y), h2 = f2bf(v23.x), h3 = f2bf(v23.y);
    Xh[o] = h0; Xh[o + 1] = h1; Xh[o + 2] = h2; Xh[o + 3] = h3;
    Xl[o]     = f2bf(v01.x - bf2f(h0));
    Xl[o + 1] = f2bf(v01.y - bf2f(h1));
    Xl[o + 2] = f2bf(v23.x - bf2f(h2));
    Xl[o + 3] = f2bf(v23.y - bf2f(h3));
  }
  __syncthreads();

  int wv = tid >> 6, lane = tid & 63;
  int c15 = lane & 15, q = lane >> 4;
  const short* arowh = Xh + (wv * 16 + c15) * 136 + q * 8;
  const short* arowl = Xl + (wv * 16 + c15) * 136 + q * 8;
  const short* wb0h = wh0 + c15 * D + q * 8;
  const short* wb0l = wl0 + c15 * D + q * 8;
  const short* wb1h = DUAL ? wh1 + c15 * D + q * 8 : nullptr;
  const short* wb1l = DUAL ? wl1 + c15 * D + q * 8 : nullptr;

  f32x4 acc0[8], acc1[8];
  #pragma unroll
  for (int t = 0; t < 8; ++t) {
    acc0[t] = (f32x4){0.f, 0.f, 0.f, 0.f};
    if (DUAL) acc1[t] = (f32x4){0.f, 0.f, 0.f, 0.f};
  }

  for (int ks = 0; ks < 4; ++ks) {
    short8v ah = *(const short8v*)(arowh + ks * 32);
    short8v al = *(const short8v*)(arowl + ks * 32);
    #pragma unroll
    for (int t = 0; t < 8; ++t) {
      short8v bh = *(const short8v*)(wb0h + t * 16 * D + ks * 32);
      short8v bl = *(const short8v*)(wb0l + t * 16 * D + ks * 32);
      acc0[t] = mfma16(ah, bh, acc0[t]);
      acc0[t] = mfma16(ah, bl, acc0[t]);
      acc0[t] = mfma16(al, bh, acc0[t]);
      if (DUAL) {
        short8v ch = *(const short8v*)(wb1h + t * 16 * D + ks * 32);
        short8v cl = *(const short8v*)(wb1l + t * 16 * D + ks * 32);
        acc1[t] = mfma16(ah, ch, acc1[t]);
        acc1[t] = mfma16(ah, cl, acc1[t]);
        acc1[t] = mfma16(al, ch, acc1[t]);
      }
    }
  }

  __syncthreads();
  float* Cb = (float*)lds_raw;
  mm_writeback(Cb, acc0, H0, row0, nrows, tid, wv, c15, q);
  if (DUAL) {
    __syncthreads();
    mm_writeback(Cb, acc1, H1, row0, nrows, tid, wv, c15, q);
  }
}

template<typename Tin>
__global__ __launch_bounds__(256) void mm_all_kernel(
    const Tin* __restrict__ Xv, const Tin* __restrict__ Xc,
    const short* __restrict__ wh0, const short* __restrict__ wl0,
    const short* __restrict__ wh1, const short* __restrict__ wl1,
    const short* __restrict__ wh2, const short* __restrict__ wl2,
    bf16* __restrict__ H0, bf16* __restrict__ H1, bf16* __restrict__ H2,
    int V, int C, int gV) {
  __shared__ __align__(16) char lds_raw[34816];
  if ((int)blockIdx.x < gV) {
    mm_block<Tin, true>(Xv, wh0, wl0, wh1, wl1, H0, H1, V, (int)blockIdx.x * 64, lds_raw);
  } else {
    mm_block<Tin, false>(Xc, wh2, wl2, nullptr, nullptr, H2, nullptr, C,
                         ((int)blockIdx.x - gV) * 64, lds_raw);
  }
}

// ---------- alpha pass: per-dst softmax -> CSR-ordered (src, alpha) pairs ----------
__device__ __forceinline__ void alpha_rel(const int* __restrict__ rp, const int* __restrict__ col,
                                          const float* __restrict__ es, float edst,
                                          int gw, int lane, int2* __restrict__ edata) {
  int p0 = rp[gw];
  int deg = rp[gw + 1] - p0;
  if (deg <= 0) return;
  if (deg <= 64) {
    int s = 0; float e = -3.0e38f;
    if (lane < deg) {
      s = col[p0 + lane];
      float t = es[s] + edst;
      e = t > 0.f ? t : 0.2f * t;
    }
    float m = e;
    #pragma unroll
    for (int off = 32; off; off >>= 1) m = fmaxf(m, __shfl_xor(m, off));
    float ex = (lane < deg) ? __expf(e - m) : 0.f;
    float den = ex;
    #pragma unroll
    for (int off = 32; off; off >>= 1) den += __shfl_xor(den, off);
    float al = ex / (den + 1e-16f);
    if (lane < deg) {
      int2 v; v.x = s; v.y = __builtin_bit_cast(int, al);
      edata[p0 + lane] = v;
    }
  } else {
    float m = -3.0e38f;
    for (int j = lane; j < deg; j += 64) {
      int s = col[p0 + j];
      float t = es[s] + edst;
      t = t > 0.f ? t : 0.2f * t;
      m = fmaxf(m, t);
    }
    #pragma unroll
    for (int off = 32; off; off >>= 1) m = fmaxf(m, __shfl_xor(m, off));
    float den = 0.f;
    for (int j = lane; j < deg; j += 64) {
      int s = col[p0 + j];
      float t = es[s] + edst;
      t = t > 0.f ? t : 0.2f * t;
      den += __expf(t - m);
    }
    #pragma unroll
    for (int off = 32; off; off >>= 1) den += __shfl_xor(den, off);
    float inv = 1.f / (den + 1e-16f);
    for (int j = lane; j < deg; j += 64) {
      int s = col[p0 + j];
      float t = es[s] + edst;
      t = t > 0.f ? t : 0.2f * t;
      int2 v; v.x = s; v.y = __builtin_bit_cast(int, __expf(t - m) * inv);
      edata[p0 + j] = v;
    }
  }
}

__global__ void alpha_all_kernel(const int* __restrict__ rp0, const int* __restrict__ col0,
                                 const float* __restrict__ es0, const float* __restrict__ ed0,
                                 int2* __restrict__ eda0,
                                 const int* __restrict__ rp2, const int* __restrict__ col2,
                                 const float* __restrict__ es2, const float* __restrict__ ed2,
                                 int2* __restrict__ eda2,
                                 const int* __restrict__ rp1, const int* __restrict__ col1,
                                 const float* __restrict__ es1, const float* __restrict__ ed1,
                                 int2* __restrict__ eda1,
                                 int V, int C) {
  int gw = (int)(((size_t)blockIdx.x * blockDim.x + threadIdx.x) >> 6);
  int lane = threadIdx.x & 63;
  if (gw < V) {
    alpha_rel(rp0, col0, es0, ed0[gw], gw, lane, eda0);
    alpha_rel(rp2, col2, es2, ed2[gw], gw, lane, eda2);
  } else if (gw < V + C) {
    int g = gw - V;
    alpha_rel(rp1, col1, es1, ed1[g], g, lane, eda1);
  }
}

// ---------- gather pass: scalar-broadcast edata, 4-deep pipelined row gathers ----------
__device__ __forceinline__ void agg_rel(const int2* __restrict__ edata, int p0, int p1,
                                        const bf16* __restrict__ hs, int l2,
                                        float& a0, float& a1) {
  int q = p0;
  while (q + 4 <= p1) {
    int2 e0 = edata[q], e1 = edata[q + 1], e2 = edata[q + 2], e3 = edata[q + 3];
    int s0 = __builtin_amdgcn_readfirstlane(e0.x);
    int s1 = __builtin_amdgcn_readfirstlane(e1.x);
    int s2 = __builtin_amdgcn_readfirstlane(e2.x);
    int s3 = __builtin_amdgcn_readfirstlane(e3.x);
    float w0 = __builtin_bit_cast(float, __builtin_amdgcn_readfirstlane(e0.y));
    float w1 = __builtin_bit_cast(float, __builtin_amdgcn_readfirstlane(e1.y));
    float w2 = __builtin_bit_cast(float, __builtin_amdgcn_readfirstlane(e2.y));
    float w3 = __builtin_bit_cast(float, __builtin_amdgcn_readfirstlane(e3.y));
    float2 h0 = ld2(&hs[(size_t)s0 * D + l2]);
    float2 h1 = ld2(&hs[(size_t)s1 * D + l2]);
    float2 h2 = ld2(&hs[(size_t)s2 * D + l2]);
    float2 h3 = ld2(&hs[(size_t)s3 * D + l2]);
    a0 += w0 * h0.x + w1 * h1.x + w2 * h2.x + w3 * h3.x;
    a1 += w0 * h0.y + w1 * h1.y + w2 * h2.y + w3 * h3.y;
    q += 4;
  }
  while (q < p1) {
    int2 e = edata[q++];
    int s = __builtin_amdgcn_readfirstlane(e.x);
    float w = __builtin_bit_cast(float, __builtin_amdgcn_readfirstlane(e.y));
    float2 h = ld2(&hs[(size_t)s * D + l2]);
    a0 += w * h.x;
    a1 += w * h.y;
  }
}

template<typename T>
__global__ void agg_all_kernel(const int* __restrict__ rp0, const int2* __restrict__ eda0,
                               const bf16* __restrict__ hsv0, const float* __restrict__ b0,
                               const int* __restrict__ rp2, const int2* __restrict__ eda2,
                               const bf16* __restrict__ hsc, const float* __restrict__ b2,
                               const int* __restrict__ rp1, const int2* __restrict__ eda1,
                               const bf16* __restrict__ hsv1, const float* __restrict__ b1,
                               T* __restrict__ xv_out, T* __restrict__ xc_out, int V, int C) {
  int gw = (int)(((size_t)blockIdx.x * blockDim.x + threadIdx.x) >> 6);
  int lane = threadIdx.x & 63;
  int l2 = 2 * lane;
  if (gw < V) {
    float a0 = 0.f, a1 = 0.f;
    agg_rel(eda0, rp0[gw], rp0[gw + 1], hsv0, l2, a0, a1);
    agg_rel(eda2, rp2[gw], rp2[gw + 1], hsc, l2, a0, a1);
    float v0 = a0 + b0[l2] + b2[l2];
    float v1 = a1 + b0[l2 + 1] + b2[l2 + 1];
    st2(&xv_out[(size_t)gw * D + l2], v0 > 0.f ? v0 : 0.f, v1 > 0.f ? v1 : 0.f);
  } else if (gw < V + C) {
    int g = gw - V;
    float a0 = 0.f, a1 = 0.f;
    agg_rel(eda1, rp1[g], rp1[g + 1], hsv1, l2, a0, a1);
    float v0 = a0 + b1[l2];
    float v1 = a1 + b1[l2 + 1];
    st2(&xc_out[(size_t)g * D + l2], v0 > 0.f ? v0 : 0.f, v1 > 0.f ? v1 : 0.f);
  }
}

// ---------- pooling over sorted batch ids ----------
template<typename T>
__global__ void pool_kernel(const T* __restrict__ xv, const int* __restrict__ batch,
                            float* __restrict__ pooled, float* __restrict__ cntf,
                            int rowsPerBlock, int V) {
  int j = threadIdx.x;
  int r0 = blockIdx.x * rowsPerBlock;
  if (r0 >= V) return;
  int rend = r0 + rowsPerBlock; if (rend > V) rend = V;
  int cur = batch[r0];
  float s = 0.f;
  int run = 0;
  for (int r = r0; r < rend; ++r) {
    int b = batch[r];
    if (b != cur) {
      atomicAdd(&pooled[(size_t)cur * D + j], s);
      if (j == 0) atomicAdd(&cntf[cur], (float)run);
      s = 0.f; run = 0; cur = b;
    }
    s += ld1(&xv[(size_t)r * D + j]);
    run++;
  }
  atomicAdd(&pooled[(size_t)cur * D + j], s);
  if (j == 0) atomicAdd(&cntf[cur], (float)run);
}

// ---------- final MLP ----------
__global__ void mlp_kernel(const float* __restrict__ pooled, const float* __restrict__ cntf,
                           const float* __restrict__ w1, const float* __restrict__ b1,
                           const float* __restrict__ w2, const float* __restrict__ b2,
                           float* __restrict__ out, int B) {
  __shared__ float P[32 * D];
  __shared__ float Hs[32 * D];
  int tid = threadIdx.x;
  if (B > 32) return;
  for (int i = tid; i < B * D; i += 256) {
    int r = i >> 7;
    P[i] = pooled[i] / fmaxf(cntf[r], 1.0f);
  }
  __syncthreads();
  for (int i = tid; i < B * D; i += 256) {
    int r = i >> 7, j = i & 127;
    float s = b1[j];
    for (int k = 0; k < D; ++k) s += P[r * D + k] * w1[k * D + j];
    Hs[i] = s > 0.f ? s : 0.f;
  }
  __syncthreads();
  if (tid < B) {
    float s = b2[0];
    for (int j = 0; j < D; ++j) s += Hs[tid * D + j] * w2[j];
    out[tid] = s;
  }
}

__global__ void zero_kernel(float* __restrict__ o, int n) {
  int i = blockIdx.x * blockDim.x + threadIdx.x;
  if (i < n) o[i] = 0.f;
}

// ---------- full pipeline ----------
template<typename T>
static void run_all(const float* x_var, const float* x_con,
                    const float* W_src, const float* W_dst,
                    const float* att_src, const float* att_dst, const float* bias,
                    const float* mlp_w1, const float* mlp_b1,
                    const float* mlp_w2, const float* mlp_b2,
                    const int* e_neg_src, const int* e_neg_dst,
                    const int* e_con_src, const int* e_con_dst, const int* batch_var,
                    int V, int C, int L, int EN, int EC, int B,
                    char* ws, float* out, hipStream_t stream) {
  size_t off = 0;
  auto alloc = [&](size_t bytes) -> char* {
    char* p = ws + off;
    off = (off + bytes + 255) & ~(size_t)255;
    return p;
  };
  T* xv  = (T*)alloc((size_t)V * D * sizeof(T));
  T* xc  = (T*)alloc((size_t)C * D * sizeof(T));
  bf16* hsv0 = (bf16*)alloc((size_t)V * D * 2);
  bf16* hsv1 = (bf16*)alloc((size_t)V * D * 2);
  bf16* hsc  = (bf16*)alloc((size_t)C * D * 2);
  float* es0 = (float*)alloc((size_t)V * 4);
  float* ed0 = (float*)alloc((size_t)V * 4);
  float* es1 = (float*)alloc((size_t)V * 4);
  float* ed2 = (float*)alloc((size_t)V * 4);
  float* es2 = (float*)alloc((size_t)C * 4);
  float* ed1 = (float*)alloc((size_t)C * 4);
  float* u   = (float*)alloc((size_t)L * 3 * 2 * D * 4);
  short* whT = (short*)alloc((size_t)L * 3 * D * D * 2);
  short* wlT = (short*)alloc((size_t)L * 3 * D * D * 2);
  int* rp0  = (int*)alloc((size_t)(V + 1) * 4);
  int* rp1  = (int*)alloc((size_t)(C + 1) * 4);
  int* rp2  = (int*)alloc((size_t)(V + 1) * 4);
  int* curs = (int*)alloc((size_t)(2 * (size_t)V + C) * 4);   // cur0 | cur1 | cur2
  int* cur0 = curs, *cur1 = curs + V, *cur2 = curs + V + C;
  int* col0 = (int*)alloc((size_t)EN * 4);
  int* col1 = (int*)alloc((size_t)EC * 4);
  int* col2 = (int*)alloc((size_t)EC * 4);
  int2* eda0 = (int2*)alloc((size_t)EN * 8);
  int2* eda1 = (int2*)alloc((size_t)EC * 8);
  int2* eda2 = (int2*)alloc((size_t)EC * 8);
  int* bsums = (int*)alloc((size_t)3 * 1024 * 4);
  float* pooled = (float*)alloc((size_t)(B * D + B) * 4);
  float* cntf = pooled + (size_t)B * D;

  hipMemsetAsync(curs, 0, (size_t)(2 * (size_t)V + C) * 4, stream);
  hipMemsetAsync(bsums, 0, (size_t)3 * 1024 * 4, stream);
  hipMemsetAsync(pooled, 0, (size_t)(B * D + B) * 4, stream);

  compute_u_kernel<<<dim3(L * 3, 2), D, 0, stream>>>(W_src, W_dst, att_src, att_dst, u);
  wsplit_kernel<<<L * 3, 256, 0, stream>>>(W_src, whT, wlT);

  const int tb = 256;
  count_kernel<<<(EN + tb - 1) / tb, tb, 0, stream>>>(e_neg_dst, cur0, EN);
  count2_kernel<<<(EC + tb - 1) / tb, tb, 0, stream>>>(e_con_src, e_con_dst, cur1, cur2, EC);

  auto pbof = [](int n) {
    int pb = ((n + 1023) / 1024 + 255) & ~255;
    return pb < 256 ? 256 : pb;
  };
  int pb0 = pbof(V), pb1 = pbof(C), pb2 = pbof(V);
  int nb0 = (V + pb0 - 1) / pb0, nb1 = (C + pb1 - 1) / pb1, nb2 = (V + pb2 - 1) / pb2;
  int nbmax = nb0 > nb1 ? nb0 : nb1; if (nb2 > nbmax) nbmax = nb2;
  bsum3_kernel<<<dim3(nbmax, 3), 256, 0, stream>>>(cur0, cur1, cur2, bsums, V, C, V, pb0, pb1, pb2);
  bscan3_kernel<<<3, 1024, 0, stream>>>(bsums, rp0 + V, rp1 + C, rp2 + V);
  scanfill3_kernel<<<dim3(nbmax, 3), 256, 0, stream>>>(cur0, cur1, cur2, bsums,
                                                       rp0, rp1, rp2, cur0, cur1, cur2,
                                                       V, C, V, pb0, pb1, pb2);

  fill_kernel<<<(EN + tb - 1) / tb, tb, 0, stream>>>(e_neg_dst, e_neg_src, cur0, col0, EN);
  fill2_kernel<<<(EC + tb - 1) / tb, tb, 0, stream>>>(e_con_src, e_con_dst, cur1, cur2, col1, col2, EC);

  auto U  = [&](int l, int rel, int side) { return u + (((size_t)l * 3 + rel) * 2 + side) * D; };
  auto Wh = [&](int l, int rel) { return whT + ((size_t)l * 3 + rel) * D * D; };
  auto Wl = [&](int l, int rel) { return wlT + ((size_t)l * 3 + rel) * D * D; };
  auto Bp = [&](int l, int rel) { return bias + ((size_t)l * 3 + rel) * D; };

  int gV = (V + 63) / 64, gC = (C + 63) / 64;
  int gwaves = (V + C + 3) / 4;

  for (int l = 0; l < L; ++l) {
    if (l == 0) {
      vec_all_kernel<float><<<gwaves, 256, 0, stream>>>(
          x_var, x_con, U(l,0,0), U(l,0,1), U(l,1,0), U(l,2,1), U(l,2,0), U(l,1,1),
          es0, ed0, es1, ed2, es2, ed1, V, C);
      mm_all_kernel<float><<<gV + gC, 256, 0, stream>>>(
          x_var, x_con, Wh(l,0), Wl(l,0), Wh(l,1), Wl(l,1), Wh(l,2), Wl(l,2),
          hsv0, hsv1, hsc, V, C, gV);
    } else {
      vec_all_kernel<T><<<gwaves, 256, 0, stream>>>(
          xv, xc, U(l,0,0), U(l,0,1), U(l,1,0), U(l,2,1), U(l,2,0), U(l,1,1),
          es0, ed0, es1, ed2, es2, ed1, V, C);
      mm_all_kernel<T><<<gV + gC, 256, 0, stream>>>(
          xv, xc, Wh(l,0), Wl(l,0), Wh(l,1), Wl(l,1), Wh(l,2), Wl(l,2),
          hsv0, hsv1, hsc, V, C, gV);
    }
    alpha_all_kernel<<<gwaves, 256, 0, stream>>>(
        rp0, col0, es0, ed0, eda0,
        rp2, col2, es2, ed2, eda2,
        rp1, col1, es1, ed1, eda1, V, C);
    agg_all_kernel<T><<<gwaves, 256, 0, stream>>>(
        rp0, eda0, hsv0, Bp(l,0),
        rp2, eda2, hsc,  Bp(l,2),
        rp1, eda1, hsv1, Bp(l,1),
        xv, xc, V, C);
  }

  pool_kernel<T><<<(V + 127) / 128, 128, 0, stream>>>(xv, batch_var, pooled, cntf, 128, V);
  mlp_kernel<<<1, 256, 0, stream>>>(pooled, cntf, mlp_w1, mlp_b1, mlp_w2, mlp_b2, out, B);
}

extern "C" void kernel_launch(void* const* d_in, const int* in_sizes, int n_in,
                              void* d_out, int out_size, void* d_ws, size_t ws_size,
                              hipStream_t stream) {
  const float* x_var   = (const float*)d_in[0];
  const float* x_con   = (const float*)d_in[1];
  const float* W_src   = (const float*)d_in[2];
  const float* W_dst   = (const float*)d_in[3];
  const float* att_src = (const float*)d_in[4];
  const float* att_dst = (const float*)d_in[5];
  const float* bias    = (const float*)d_in[6];
  const float* mlp_w1  = (const float*)d_in[7];
  const float* mlp_b1  = (const float*)d_in[8];
  const float* mlp_w2  = (const float*)d_in[9];
  const float* mlp_b2  = (const float*)d_in[10];
  const int* e_neg_src = (const int*)d_in[11];
  const int* e_neg_dst = (const int*)d_in[12];
  const int* e_con_src = (const int*)d_in[13];
  const int* e_con_dst = (const int*)d_in[14];
  const int* batch_var = (const int*)d_in[15];
  (void)n_in;

  const int V  = in_sizes[0] / D;
  const int C  = in_sizes[1] / D;
  const int L  = in_sizes[2] / (3 * D * D);
  const int EN = in_sizes[11];
  const int EC = in_sizes[13];
  const int B  = out_size;

  auto plan = [&](size_t esz) -> size_t {
    size_t o = 0;
    auto add = [&](size_t b) { o = (o + b + 255) & ~(size_t)255; };
    add((size_t)V * D * esz); add((size_t)C * D * esz);
    add((size_t)V * D * 2); add((size_t)V * D * 2); add((size_t)C * D * 2);
    add((size_t)V * 4); add((size_t)V * 4); add((size_t)V * 4); add((size_t)V * 4);
    add((size_t)C * 4); add((size_t)C * 4);
    add((size_t)L * 3 * 2 * D * 4);
    add((size_t)L * 3 * D * D * 2); add((size_t)L * 3 * D * D * 2);
    add((size_t)(V + 1) * 4); add((size_t)(C + 1) * 4); add((size_t)(V + 1) * 4);
    add((size_t)(2 * (size_t)V + C) * 4);
    add((size_t)EN * 4); add((size_t)EC * 4); add((size_t)EC * 4);
    add((size_t)EN * 8); add((size_t)EC * 8); add((size_t)EC * 8);
    add((size_t)3 * 1024 * 4);
    add((size_t)(B * D + B) * 4);
    return o;
  };

  if (plan(4) <= ws_size) {
    run_all<float>(x_var, x_con, W_src, W_dst, att_src, att_dst, bias,
                   mlp_w1, mlp_b1, mlp_w2, mlp_b2,
                   e_neg_src, e_neg_dst, e_con_src, e_con_dst, batch_var,
                   V, C, L, EN, EC, B, (char*)d_ws, (float*)d_out, stream);
  } else if (plan(2) <= ws_size) {
    run_all<bf16>(x_var, x_con, W_src, W_dst, att_src, att_dst, bias,
                  mlp_w1, mlp_b1, mlp_w2, mlp_b2,
                  e_neg_src, e_neg_dst, e_con_src, e_con_dst, batch_var,
                  V, C, L, EN, EC, B, (char*)d_ws, (float*)d_out, stream);
  } else {
    zero_kernel<<<(out_size + 63) / 64, 64, 0, stream>>>((float*)d_out, out_size);
  }
}

// Round 7
// 1027.081 us; speedup vs baseline: 1.3942x; 1.3942x over previous
//
#include <hip/hip_runtime.h>
#include <hip/hip_bf16.h>
#include <cstdint>
#include <cstddef>

#define D 128

typedef __hip_bfloat16 bf16;
typedef __attribute__((ext_vector_type(8))) short short8v;   // 8 bf16 (4 VGPR)
typedef __attribute__((ext_vector_type(4))) float f32x4;     // MFMA 16x16 acc

// ---------- typed load/store helpers ----------
__device__ inline float ld1(const float* p) { return *p; }
__device__ inline float ld1(const bf16* p) { return __bfloat162float(*p); }
__device__ inline float2 ld2(const float* p) { return *(const float2*)p; }
__device__ inline float2 ld2(const bf16* p) {
  __hip_bfloat162 v = *(const __hip_bfloat162*)p;
  float2 r; r.x = __bfloat162float(v.x); r.y = __bfloat162float(v.y); return r;
}
__device__ inline void st2(float* p, float a, float b) {
  float2 v; v.x = a; v.y = b; *(float2*)p = v;
}
__device__ inline void st2(bf16* p, float a, float b) {
  __hip_bfloat162 v; v.x = __float2bfloat16(a); v.y = __float2bfloat16(b);
  *(__hip_bfloat162*)p = v;
}

// bf16 bit helpers (RNE)
__device__ inline short f2bf(float x) {
  uint32_t u = __builtin_bit_cast(uint32_t, x);
  uint32_t r = (u + 0x7FFFu + ((u >> 16) & 1u)) >> 16;
  return (short)(uint16_t)r;
}
__device__ inline float bf2f(short s) {
  uint32_t u = ((uint32_t)(uint16_t)s) << 16;
  return __builtin_bit_cast(float, u);
}

__device__ inline f32x4 mfma16(short8v a, short8v b, f32x4 c) {
  return __builtin_amdgcn_mfma_f32_16x16x32_bf16(a, b, c, 0, 0, 0);
}

__device__ __forceinline__ void load8(const float* p, float* v) {
  float4 a = *(const float4*)p;
  float4 b = *(const float4*)(p + 4);
  v[0] = a.x; v[1] = a.y; v[2] = a.z; v[3] = a.w;
  v[4] = b.x; v[5] = b.y; v[6] = b.z; v[7] = b.w;
}
__device__ __forceinline__ void load8(const bf16* p, float* v) {
  short8v s = *(const short8v*)p;
  #pragma unroll
  for (int j = 0; j < 8; ++j) v[j] = bf2f(s[j]);
}
__device__ __forceinline__ void split_store(short* Xh, short* Xl, int off, const float* v) {
  short8v h, l;
  #pragma unroll
  for (int j = 0; j < 8; ++j) {
    short hj = f2bf(v[j]);
    h[j] = hj;
    l[j] = f2bf(v[j] - bf2f(hj));
  }
  *(short8v*)&Xh[off] = h;
  *(short8v*)&Xl[off] = l;
}

// ---------- u[l,rel,side][k] = sum_j W[l,rel,k,j] * a[l,rel,j] ----------
__global__ void compute_u_kernel(const float* __restrict__ Wsrc, const float* __restrict__ Wdst,
                                 const float* __restrict__ asrc, const float* __restrict__ adst,
                                 float* __restrict__ u) {
  int lr = blockIdx.x;
  int side = blockIdx.y;
  int k = threadIdx.x;
  const float* W = (side == 0 ? Wsrc : Wdst) + ((size_t)lr * D + k) * D;
  const float* a = (side == 0 ? asrc : adst) + (size_t)lr * D;
  float s = 0.f;
  for (int j = 0; j < D; ++j) s += W[j] * a[j];
  u[((size_t)lr * 2 + side) * D + k] = s;
}

// ---------- W split: Wh/Wl bf16, transposed [col][k] ----------
__global__ void wsplit_kernel(const float* __restrict__ Wsrc,
                              short* __restrict__ WhT, short* __restrict__ WlT) {
  int lr = blockIdx.x;
  const float* W = Wsrc + (size_t)lr * D * D;
  short* wh = WhT + (size_t)lr * D * D;
  short* wl = WlT + (size_t)lr * D * D;
  for (int i = threadIdx.x; i < D * D; i += blockDim.x) {
    int k = i >> 7, c = i & 127;
    float w = W[i];
    short h = f2bf(w);
    short l = f2bf(w - bf2f(h));
    wh[c * D + k] = h;
    wl[c * D + k] = l;
  }
}

// ---------- CSR build ----------
__global__ void count_kernel(const int* __restrict__ dst, int* __restrict__ cnt, int E) {
  int i = blockIdx.x * blockDim.x + threadIdx.x;
  if (i < E) atomicAdd(&cnt[dst[i]], 1);
}

__global__ void count2_kernel(const int* __restrict__ csrc, const int* __restrict__ cdst,
                              int* __restrict__ cnt_bycon, int* __restrict__ cnt_byvar, int E) {
  int i = blockIdx.x * blockDim.x + threadIdx.x;
  if (i < E) {
    atomicAdd(&cnt_bycon[cdst[i]], 1);
    atomicAdd(&cnt_byvar[csrc[i]], 1);
  }
}

__global__ void bsum3_kernel(const int* __restrict__ c0, const int* __restrict__ c1,
                             const int* __restrict__ c2, int* __restrict__ bsums,
                             int n0, int n1, int n2, int pb0, int pb1, int pb2) {
  __shared__ int red[256];
  int y = blockIdx.y;
  const int* cnt = (y == 0) ? c0 : (y == 1) ? c1 : c2;
  int n  = (y == 0) ? n0 : (y == 1) ? n1 : n2;
  int pb = (y == 0) ? pb0 : (y == 1) ? pb1 : pb2;
  int b = blockIdx.x, t = threadIdx.x;
  int base = b * pb;
  if (base >= n) return;
  int end = base + pb; if (end > n) end = n;
  int s = 0;
  for (int i = base + t; i < end; i += 256) s += cnt[i];
  red[t] = s;
  __syncthreads();
  #pragma unroll
  for (int off = 128; off; off >>= 1) {
    if (t < off) red[t] += red[t + off];
    __syncthreads();
  }
  if (t == 0) bsums[y * 1024 + b] = red[0];
}

__global__ void bscan3_kernel(int* __restrict__ bsums,
                              int* __restrict__ t0, int* __restrict__ t1, int* __restrict__ t2) {
  __shared__ int sh[1024];
  int y = blockIdx.x, t = threadIdx.x;
  int* bs = bsums + y * 1024;
  int v = bs[t];
  sh[t] = v;
  __syncthreads();
  for (int off = 1; off < 1024; off <<= 1) {
    int u = (t >= off) ? sh[t - off] : 0;
    __syncthreads();
    sh[t] += u;
    __syncthreads();
  }
  bs[t] = sh[t] - v;
  if (t == 1023) {
    int* tot = (y == 0) ? t0 : (y == 1) ? t1 : t2;
    *tot = sh[1023];
  }
}

__global__ void scanfill3_kernel(const int* __restrict__ c0, const int* __restrict__ c1,
                                 const int* __restrict__ c2, const int* __restrict__ bsums,
                                 int* __restrict__ rp0, int* __restrict__ rp1, int* __restrict__ rp2,
                                 int* __restrict__ cu0, int* __restrict__ cu1, int* __restrict__ cu2,
                                 int n0, int n1, int n2, int pb0, int pb1, int pb2) {
  __shared__ int sh[256];
  int y = blockIdx.y;
  const int* cnt = (y == 0) ? c0 : (y == 1) ? c1 : c2;
  int* rowptr    = (y == 0) ? rp0 : (y == 1) ? rp1 : rp2;
  int* cursor    = (y == 0) ? cu0 : (y == 1) ? cu1 : cu2;
  int n  = (y == 0) ? n0 : (y == 1) ? n1 : n2;
  int pb = (y == 0) ? pb0 : (y == 1) ? pb1 : pb2;
  int b = blockIdx.x, t = threadIdx.x;
  int base = b * pb;
  if (base >= n) return;
  int end = base + pb; if (end > n) end = n;
  int run = bsums[y * 1024 + b];
  for (int tile = base; tile < end; tile += 256) {
    int i = tile + t;
    int c = (i < end) ? cnt[i] : 0;
    __syncthreads();
    sh[t] = c;
    __syncthreads();
    for (int off = 1; off < 256; off <<= 1) {
      int u = (t >= off) ? sh[t - off] : 0;
      __syncthreads();
      sh[t] += u;
      __syncthreads();
    }
    int excl = sh[t] - c;
    if (i < end) {
      rowptr[i] = run + excl;
      cursor[i] = run + excl;
    }
    run += sh[255];
  }
}

__global__ void fill_kernel(const int* __restrict__ dst, const int* __restrict__ src,
                            int* __restrict__ cursor, int* __restrict__ col, int E) {
  int i = blockIdx.x * blockDim.x + threadIdx.x;
  if (i < E) {
    int p = atomicAdd(&cursor[dst[i]], 1);
    col[p] = src[i];
  }
}

__global__ void fill2_kernel(const int* __restrict__ csrc, const int* __restrict__ cdst,
                             int* __restrict__ cur_bycon, int* __restrict__ cur_byvar,
                             int* __restrict__ col_bycon, int* __restrict__ col_byvar, int E) {
  int i = blockIdx.x * blockDim.x + threadIdx.x;
  if (i < E) {
    int s = csrc[i], d = cdst[i];
    int p = atomicAdd(&cur_bycon[d], 1);
    col_bycon[p] = s;
    int q = atomicAdd(&cur_byvar[s], 1);
    col_byvar[q] = d;
  }
}

// ---------- merged matvec bundles ----------
template<typename T>
__global__ void vec_all_kernel(const T* __restrict__ xv, const T* __restrict__ xc,
                               const float* __restrict__ uv0, const float* __restrict__ uv1,
                               const float* __restrict__ uv2, const float* __restrict__ uv3,
                               const float* __restrict__ uc0, const float* __restrict__ uc1,
                               float* __restrict__ es0, float* __restrict__ ed0,
                               float* __restrict__ es1, float* __restrict__ ed2,
                               float* __restrict__ es2, float* __restrict__ ed1,
                               int V, int C) {
  int gw = (int)(((size_t)blockIdx.x * blockDim.x + threadIdx.x) >> 6);
  int lane = threadIdx.x & 63;
  if (gw < V) {
    const T* xr = xv + (size_t)gw * D;
    float xa = ld1(&xr[lane]), xb = ld1(&xr[lane + 64]);
    float p0 = xa * uv0[lane] + xb * uv0[lane + 64];
    float p1 = xa * uv1[lane] + xb * uv1[lane + 64];
    float p2 = xa * uv2[lane] + xb * uv2[lane + 64];
    float p3 = xa * uv3[lane] + xb * uv3[lane + 64];
    #pragma unroll
    for (int off = 32; off; off >>= 1) {
      p0 += __shfl_xor(p0, off);
      p1 += __shfl_xor(p1, off);
      p2 += __shfl_xor(p2, off);
      p3 += __shfl_xor(p3, off);
    }
    if (lane == 0) { es0[gw] = p0; ed0[gw] = p1; es1[gw] = p2; ed2[gw] = p3; }
  } else if (gw < V + C) {
    int g = gw - V;
    const T* xr = xc + (size_t)g * D;
    float xa = ld1(&xr[lane]), xb = ld1(&xr[lane + 64]);
    float p0 = xa * uc0[lane] + xb * uc0[lane + 64];
    float p1 = xa * uc1[lane] + xb * uc1[lane + 64];
    #pragma unroll
    for (int off = 32; off; off >>= 1) {
      p0 += __shfl_xor(p0, off);
      p1 += __shfl_xor(p1, off);
    }
    if (lane == 0) { es2[g] = p0; ed1[g] = p1; }
  }
}

// ---------- mm3: all three matmuls, W-fragments register-resident ----------
// block = 512 thr (8 waves = 2 rowgrp x 4 colgrp); chunk = 32 rows x 128 cols.
// Swapped MFMA operands: A = W-frag (output cols in acc regs), B = X-frag.
// Grid-stride over chunks amortizes the one-time W register load.
template<typename Tin>
__global__ __launch_bounds__(512) void mm3_kernel(
    const Tin* __restrict__ Xv, const Tin* __restrict__ Xc,
    const short* __restrict__ wh0, const short* __restrict__ wl0,
    const short* __restrict__ wh1, const short* __restrict__ wl1,
    const short* __restrict__ wh2, const short* __restrict__ wl2,
    bf16* __restrict__ H0, bf16* __restrict__ H1, bf16* __restrict__ H2,
    int V, int C, int b0, int b1, int b2) {
  __shared__ short sbuf[2][2][32 * 136];   // [buf][h/l][row*136+k], 34816 B
  int bid = blockIdx.x;
  const Tin* X; const short* wh; const short* wl; bf16* H;
  int nrows, lb, nblk;
  if (bid < b0)      { X = Xv; wh = wh0; wl = wl0; H = H0; nrows = V; lb = bid;      nblk = b0; }
  else if (bid < b1) { X = Xv; wh = wh1; wl = wl1; H = H1; nrows = V; lb = bid - b0; nblk = b1 - b0; }
  else               { X = Xc; wh = wh2; wl = wl2; H = H2; nrows = C; lb = bid - b1; nblk = b2 - b1; }
  int nchunks = nrows >> 5;
  if (lb >= nchunks) return;

  int tid = threadIdx.x;
  int wv = tid >> 6, lane = tid & 63;
  int c15 = lane & 15, q = lane >> 4;
  int rowgrp = wv >> 2, colgrp = wv & 3;

  // one-time W fragment load -> registers (A-operand role)
  short8v Bh[2][4], Bl[2][4];
  #pragma unroll
  for (int t = 0; t < 2; ++t) {
    #pragma unroll
    for (int ks = 0; ks < 4; ++ks) {
      int o = (colgrp * 32 + t * 16 + c15) * D + ks * 32 + q * 8;
      Bh[t][ks] = *(const short8v*)&wh[o];
      Bl[t][ks] = *(const short8v*)&wl[o];
    }
  }

  int srow = tid >> 4;            // 0..31
  int scol = (tid & 15) * 8;      // 0..120
  int soff = srow * 136 + scol;

  {  // prologue: stage first chunk into buf 0
    float v[8];
    int gr = lb * 32 + srow; if (gr >= nrows) gr = nrows - 1;
    load8(X + (size_t)gr * D + scol, v);
    split_store(&sbuf[0][0][0], &sbuf[0][1][0], soff, v);
  }
  __syncthreads();

  int aoff = (rowgrp * 16 + c15) * 136 + q * 8;
  int cur = 0;
  for (int chunk = lb; chunk < nchunks; chunk += nblk) {
    int nxt = chunk + nblk;
    bool have = nxt < nchunks;
    float v[8];
    if (have) {
      int gr = nxt * 32 + srow; if (gr >= nrows) gr = nrows - 1;
      load8(X + (size_t)gr * D + scol, v);
    }
    const short* Ah = &sbuf[cur][0][aoff];
    const short* Al = &sbuf[cur][1][aoff];
    f32x4 a0 = (f32x4){0.f, 0.f, 0.f, 0.f};
    f32x4 a1 = (f32x4){0.f, 0.f, 0.f, 0.f};
    #pragma unroll
    for (int ks = 0; ks < 4; ++ks) {
      short8v xh = *(const short8v*)(Ah + ks * 32);
      short8v xl = *(const short8v*)(Al + ks * 32);
      a0 = mfma16(Bh[0][ks], xh, a0);
      a1 = mfma16(Bh[1][ks], xh, a1);
      a0 = mfma16(Bl[0][ks], xh, a0);
      a1 = mfma16(Bl[1][ks], xh, a1);
      a0 = mfma16(Bh[0][ks], xl, a0);
      a1 = mfma16(Bh[1][ks], xl, a1);
    }
    int gr = chunk * 32 + rowgrp * 16 + c15;
    if (gr < nrows) {
      short4 o0, o1;
      o0.x = f2bf(a0[0]); o0.y = f2bf(a0[1]); o0.z = f2bf(a0[2]); o0.w = f2bf(a0[3]);
      o1.x = f2bf(a1[0]); o1.y = f2bf(a1[1]); o1.z = f2bf(a1[2]); o1.w = f2bf(a1[3]);
      size_t base = (size_t)gr * D + colgrp * 32 + q * 4;
      *(short4*)((short*)H + base) = o0;
      *(short4*)((short*)H + base + 16) = o1;
    }
    if (have) split_store(&sbuf[cur ^ 1][0][0], &sbuf[cur ^ 1][1][0], soff, v);
    __syncthreads();
    cur ^= 1;
  }
}

// ---------- alpha pass: per-dst softmax -> CSR-ordered (src, alpha) pairs ----------
__device__ __forceinline__ void alpha_rel(const int* __restrict__ rp, const int* __restrict__ col,
                                          const float* __restrict__ es, float edst,
                                          int gw, int lane, int2* __restrict__ edata) {
  int p0 = rp[gw];
  int deg = rp[gw + 1] - p0;
  if (deg <= 0) return;
  if (deg <= 64) {
    int s = 0; float e = -3.0e38f;
    if (lane < deg) {
      s = col[p0 + lane];
      float t = es[s] + edst;
      e = t > 0.f ? t : 0.2f * t;
    }
    float m = e;
    #pragma unroll
    for (int off = 32; off; off >>= 1) m = fmaxf(m, __shfl_xor(m, off));
    float ex = (lane < deg) ? __expf(e - m) : 0.f;
    float den = ex;
    #pragma unroll
    for (int off = 32; off; off >>= 1) den += __shfl_xor(den, off);
    float al = ex / (den + 1e-16f);
    if (lane < deg) {
      int2 v; v.x = s; v.y = __builtin_bit_cast(int, al);
      edata[p0 + lane] = v;
    }
  } else {
    float m = -3.0e38f;
    for (int j = lane; j < deg; j += 64) {
      int s = col[p0 + j];
      float t = es[s] + edst;
      t = t > 0.f ? t : 0.2f * t;
      m = fmaxf(m, t);
    }
    #pragma unroll
    for (int off = 32; off; off >>= 1) m = fmaxf(m, __shfl_xor(m, off));
    float den = 0.f;
    for (int j = lane; j < deg; j += 64) {
      int s = col[p0 + j];
      float t = es[s] + edst;
      t = t > 0.f ? t : 0.2f * t;
      den += __expf(t - m);
    }
    #pragma unroll
    for (int off = 32; off; off >>= 1) den += __shfl_xor(den, off);
    float inv = 1.f / (den + 1e-16f);
    for (int j = lane; j < deg; j += 64) {
      int s = col[p0 + j];
      float t = es[s] + edst;
      t = t > 0.f ? t : 0.2f * t;
      int2 v; v.x = s; v.y = __builtin_bit_cast(int, __expf(t - m) * inv);
      edata[p0 + j] = v;
    }
  }
}

__global__ void alpha_all_kernel(const int* __restrict__ rp0, const int* __restrict__ col0,
                                 const float* __restrict__ es0, const float* __restrict__ ed0,
                                 int2* __restrict__ eda0,
                                 const int* __restrict__ rp2, const int* __restrict__ col2,
                                 const float* __restrict__ es2, const float* __restrict__ ed2,
                                 int2* __restrict__ eda2,
                                 const int* __restrict__ rp1, const int* __restrict__ col1,
                                 const float* __restrict__ es1, const float* __restrict__ ed1,
                                 int2* __restrict__ eda1,
                                 int V, int C) {
  int gw = (int)(((size_t)blockIdx.x * blockDim.x + threadIdx.x) >> 6);
  int lane = threadIdx.x & 63;
  if (gw < V) {
    alpha_rel(rp0, col0, es0, ed0[gw], gw, lane, eda0);
    alpha_rel(rp2, col2, es2, ed2[gw], gw, lane, eda2);
  } else if (gw < V + C) {
    int g = gw - V;
    alpha_rel(rp1, col1, es1, ed1[g], g, lane, eda1);
  }
}

// ---------- gather pass ----------
__device__ __forceinline__ void agg_rel(const int2* __restrict__ edata, int p0, int p1,
                                        const bf16* __restrict__ hs, int l2,
                                        float& a0, float& a1) {
  int q = p0;
  while (q + 4 <= p1) {
    int2 e0 = edata[q], e1 = edata[q + 1], e2 = edata[q + 2], e3 = edata[q + 3];
    int s0 = __builtin_amdgcn_readfirstlane(e0.x);
    int s1 = __builtin_amdgcn_readfirstlane(e1.x);
    int s2 = __builtin_amdgcn_readfirstlane(e2.x);
    int s3 = __builtin_amdgcn_readfirstlane(e3.x);
    float w0 = __builtin_bit_cast(float, __builtin_amdgcn_readfirstlane(e0.y));
    float w1 = __builtin_bit_cast(float, __builtin_amdgcn_readfirstlane(e1.y));
    float w2 = __builtin_bit_cast(float, __builtin_amdgcn_readfirstlane(e2.y));
    float w3 = __builtin_bit_cast(float, __builtin_amdgcn_readfirstlane(e3.y));
    float2 h0 = ld2(&hs[(size_t)s0 * D + l2]);
    float2 h1 = ld2(&hs[(size_t)s1 * D + l2]);
    float2 h2 = ld2(&hs[(size_t)s2 * D + l2]);
    float2 h3 = ld2(&hs[(size_t)s3 * D + l2]);
    a0 += w0 * h0.x + w1 * h1.x + w2 * h2.x + w3 * h3.x;
    a1 += w0 * h0.y + w1 * h1.y + w2 * h2.y + w3 * h3.y;
    q += 4;
  }
  while (q < p1) {
    int2 e = edata[q++];
    int s = __builtin_amdgcn_readfirstlane(e.x);
    float w = __builtin_bit_cast(float, __builtin_amdgcn_readfirstlane(e.y));
    float2 h = ld2(&hs[(size_t)s * D + l2]);
    a0 += w * h.x;
    a1 += w * h.y;
  }
}

template<typename T>
__global__ void agg_all_kernel(const int* __restrict__ rp0, const int2* __restrict__ eda0,
                               const bf16* __restrict__ hsv0, const float* __restrict__ b0,
                               const int* __restrict__ rp2, const int2* __restrict__ eda2,
                               const bf16* __restrict__ hsc, const float* __restrict__ b2,
                               const int* __restrict__ rp1, const int2* __restrict__ eda1,
                               const bf16* __restrict__ hsv1, const float* __restrict__ b1,
                               T* __restrict__ xv_out, T* __restrict__ xc_out, int V, int C) {
  int gw = (int)(((size_t)blockIdx.x * blockDim.x + threadIdx.x) >> 6);
  int lane = threadIdx.x & 63;
  int l2 = 2 * lane;
  if (gw < V) {
    float a0 = 0.f, a1 = 0.f;
    agg_rel(eda0, rp0[gw], rp0[gw + 1], hsv0, l2, a0, a1);
    agg_rel(eda2, rp2[gw], rp2[gw + 1], hsc, l2, a0, a1);
    float v0 = a0 + b0[l2] + b2[l2];
    float v1 = a1 + b0[l2 + 1] + b2[l2 + 1];
    st2(&xv_out[(size_t)gw * D + l2], v0 > 0.f ? v0 : 0.f, v1 > 0.f ? v1 : 0.f);
  } else if (gw < V + C) {
    int g = gw - V;
    float a0 = 0.f, a1 = 0.f;
    agg_rel(eda1, rp1[g], rp1[g + 1], hsv1, l2, a0, a1);
    float v0 = a0 + b1[l2];
    float v1 = a1 + b1[l2 + 1];
    st2(&xc_out[(size_t)g * D + l2], v0 > 0.f ? v0 : 0.f, v1 > 0.f ? v1 : 0.f);
  }
}

// ---------- pooling over sorted batch ids ----------
template<typename T>
__global__ void pool_kernel(const T* __restrict__ xv, const int* __restrict__ batch,
                            float* __restrict__ pooled, float* __restrict__ cntf,
                            int rowsPerBlock, int V) {
  int j = threadIdx.x;
  int r0 = blockIdx.x * rowsPerBlock;
  if (r0 >= V) return;
  int rend = r0 + rowsPerBlock; if (rend > V) rend = V;
  int cur = batch[r0];
  float s = 0.f;
  int run = 0;
  for (int r = r0; r < rend; ++r) {
    int b = batch[r];
    if (b != cur) {
      atomicAdd(&pooled[(size_t)cur * D + j], s);
      if (j == 0) atomicAdd(&cntf[cur], (float)run);
      s = 0.f; run = 0; cur = b;
    }
    s += ld1(&xv[(size_t)r * D + j]);
    run++;
  }
  atomicAdd(&pooled[(size_t)cur * D + j], s);
  if (j == 0) atomicAdd(&cntf[cur], (float)run);
}

// ---------- final MLP ----------
__global__ void mlp_kernel(const float* __restrict__ pooled, const float* __restrict__ cntf,
                           const float* __restrict__ w1, const float* __restrict__ b1,
                           const float* __restrict__ w2, const float* __restrict__ b2,
                           float* __restrict__ out, int B) {
  __shared__ float P[32 * D];
  __shared__ float Hs[32 * D];
  int tid = threadIdx.x;
  if (B > 32) return;
  for (int i = tid; i < B * D; i += 256) {
    int r = i >> 7;
    P[i] = pooled[i] / fmaxf(cntf[r], 1.0f);
  }
  __syncthreads();
  for (int i = tid; i < B * D; i += 256) {
    int r = i >> 7, j = i & 127;
    float s = b1[j];
    for (int k = 0; k < D; ++k) s += P[r * D + k] * w1[k * D + j];
    Hs[i] = s > 0.f ? s : 0.f;
  }
  __syncthreads();
  if (tid < B) {
    float s = b2[0];
    for (int j = 0; j < D; ++j) s += Hs[tid * D + j] * w2[j];
    out[tid] = s;
  }
}

__global__ void zero_kernel(float* __restrict__ o, int n) {
  int i = blockIdx.x * blockDim.x + threadIdx.x;
  if (i < n) o[i] = 0.f;
}

// ---------- full pipeline ----------
template<typename T>
static void run_all(const float* x_var, const float* x_con,
                    const float* W_src, const float* W_dst,
                    const float* att_src, const float* att_dst, const float* bias,
                    const float* mlp_w1, const float* mlp_b1,
                    const float* mlp_w2, const float* mlp_b2,
                    const int* e_neg_src, const int* e_neg_dst,
                    const int* e_con_src, const int* e_con_dst, const int* batch_var,
                    int V, int C, int L, int EN, int EC, int B,
                    char* ws, float* out, hipStream_t stream) {
  size_t off = 0;
  auto alloc = [&](size_t bytes) -> char* {
    char* p = ws + off;
    off = (off + bytes + 255) & ~(size_t)255;
    return p;
  };
  T* xv  = (T*)alloc((size_t)V * D * sizeof(T));
  T* xc  = (T*)alloc((size_t)C * D * sizeof(T));
  bf16* hsv0 = (bf16*)alloc((size_t)V * D * 2);
  bf16* hsv1 = (bf16*)alloc((size_t)V * D * 2);
  bf16* hsc  = (bf16*)alloc((size_t)C * D * 2);
  float* es0 = (float*)alloc((size_t)V * 4);
  float* ed0 = (float*)alloc((size_t)V * 4);
  float* es1 = (float*)alloc((size_t)V * 4);
  float* ed2 = (float*)alloc((size_t)V * 4);
  float* es2 = (float*)alloc((size_t)C * 4);
  float* ed1 = (float*)alloc((size_t)C * 4);
  float* u   = (float*)alloc((size_t)L * 3 * 2 * D * 4);
  short* whT = (short*)alloc((size_t)L * 3 * D * D * 2);
  short* wlT = (short*)alloc((size_t)L * 3 * D * D * 2);
  int* rp0  = (int*)alloc((size_t)(V + 1) * 4);
  int* rp1  = (int*)alloc((size_t)(C + 1) * 4);
  int* rp2  = (int*)alloc((size_t)(V + 1) * 4);
  int* curs = (int*)alloc((size_t)(2 * (size_t)V + C) * 4);
  int* cur0 = curs, *cur1 = curs + V, *cur2 = curs + V + C;
  int* col0 = (int*)alloc((size_t)EN * 4);
  int* col1 = (int*)alloc((size_t)EC * 4);
  int* col2 = (int*)alloc((size_t)EC * 4);
  int2* eda0 = (int2*)alloc((size_t)EN * 8);
  int2* eda1 = (int2*)alloc((size_t)EC * 8);
  int2* eda2 = (int2*)alloc((size_t)EC * 8);
  int* bsums = (int*)alloc((size_t)3 * 1024 * 4);
  float* pooled = (float*)alloc((size_t)(B * D + B) * 4);
  float* cntf = pooled + (size_t)B * D;

  hipMemsetAsync(curs, 0, (size_t)(2 * (size_t)V + C) * 4, stream);
  hipMemsetAsync(bsums, 0, (size_t)3 * 1024 * 4, stream);
  hipMemsetAsync(pooled, 0, (size_t)(B * D + B) * 4, stream);

  compute_u_kernel<<<dim3(L * 3, 2), D, 0, stream>>>(W_src, W_dst, att_src, att_dst, u);
  wsplit_kernel<<<L * 3, 256, 0, stream>>>(W_src, whT, wlT);

  const int tb = 256;
  count_kernel<<<(EN + tb - 1) / tb, tb, 0, stream>>>(e_neg_dst, cur0, EN);
  count2_kernel<<<(EC + tb - 1) / tb, tb, 0, stream>>>(e_con_src, e_con_dst, cur1, cur2, EC);

  auto pbof = [](int n) {
    int pb = ((n + 1023) / 1024 + 255) & ~255;
    return pb < 256 ? 256 : pb;
  };
  int pb0 = pbof(V), pb1 = pbof(C), pb2 = pbof(V);
  int nb0 = (V + pb0 - 1) / pb0, nb1 = (C + pb1 - 1) / pb1, nb2 = (V + pb2 - 1) / pb2;
  int nbmax = nb0 > nb1 ? nb0 : nb1; if (nb2 > nbmax) nbmax = nb2;
  bsum3_kernel<<<dim3(nbmax, 3), 256, 0, stream>>>(cur0, cur1, cur2, bsums, V, C, V, pb0, pb1, pb2);
  bscan3_kernel<<<3, 1024, 0, stream>>>(bsums, rp0 + V, rp1 + C, rp2 + V);
  scanfill3_kernel<<<dim3(nbmax, 3), 256, 0, stream>>>(cur0, cur1, cur2, bsums,
                                                       rp0, rp1, rp2, cur0, cur1, cur2,
                                                       V, C, V, pb0, pb1, pb2);

  fill_kernel<<<(EN + tb - 1) / tb, tb, 0, stream>>>(e_neg_dst, e_neg_src, cur0, col0, EN);
  fill2_kernel<<<(EC + tb - 1) / tb, tb, 0, stream>>>(e_con_src, e_con_dst, cur1, cur2, col1, col2, EC);

  auto U  = [&](int l, int rel, int side) { return u + (((size_t)l * 3 + rel) * 2 + side) * D; };
  auto Wh = [&](int l, int rel) { return whT + ((size_t)l * 3 + rel) * D * D; };
  auto Wl = [&](int l, int rel) { return wlT + ((size_t)l * 3 + rel) * D * D; };
  auto Bp = [&](int l, int rel) { return bias + ((size_t)l * 3 + rel) * D; };

  int gwaves = (V + C + 3) / 4;
  const int MB0 = 512, MB1 = 1024, MB2 = 1280;   // mm3 block ranges

  for (int l = 0; l < L; ++l) {
    if (l == 0) {
      vec_all_kernel<float><<<gwaves, 256, 0, stream>>>(
          x_var, x_con, U(l,0,0), U(l,0,1), U(l,1,0), U(l,2,1), U(l,2,0), U(l,1,1),
          es0, ed0, es1, ed2, es2, ed1, V, C);
      mm3_kernel<float><<<MB2, 512, 0, stream>>>(
          x_var, x_con, Wh(l,0), Wl(l,0), Wh(l,1), Wl(l,1), Wh(l,2), Wl(l,2),
          hsv0, hsv1, hsc, V, C, MB0, MB1, MB2);
    } else {
      vec_all_kernel<T><<<gwaves, 256, 0, stream>>>(
          xv, xc, U(l,0,0), U(l,0,1), U(l,1,0), U(l,2,1), U(l,2,0), U(l,1,1),
          es0, ed0, es1, ed2, es2, ed1, V, C);
      mm3_kernel<T><<<MB2, 512, 0, stream>>>(
          xv, xc, Wh(l,0), Wl(l,0), Wh(l,1), Wl(l,1), Wh(l,2), Wl(l,2),
          hsv0, hsv1, hsc, V, C, MB0, MB1, MB2);
    }
    alpha_all_kernel<<<gwaves, 256, 0, stream>>>(
        rp0, col0, es0, ed0, eda0,
        rp2, col2, es2, ed2, eda2,
        rp1, col1, es1, ed1, eda1, V, C);
    agg_all_kernel<T><<<gwaves, 256, 0, stream>>>(
        rp0, eda0, hsv0, Bp(l,0),
        rp2, eda2, hsc,  Bp(l,2),
        rp1, eda1, hsv1, Bp(l,1),
        xv, xc, V, C);
  }

  pool_kernel<T><<<(V + 127) / 128, 128, 0, stream>>>(xv, batch_var, pooled, cntf, 128, V);
  mlp_kernel<<<1, 256, 0, stream>>>(pooled, cntf, mlp_w1, mlp_b1, mlp_w2, mlp_b2, out, B);
}

extern "C" void kernel_launch(void* const* d_in, const int* in_sizes, int n_in,
                              void* d_out, int out_size, void* d_ws, size_t ws_size,
                              hipStream_t stream) {
  const float* x_var   = (const float*)d_in[0];
  const float* x_con   = (const float*)d_in[1];
  const float* W_src   = (const float*)d_in[2];
  const float* W_dst   = (const float*)d_in[3];
  const float* att_src = (const float*)d_in[4];
  const float* att_dst = (const float*)d_in[5];
  const float* bias    = (const float*)d_in[6];
  const float* mlp_w1  = (const float*)d_in[7];
  const float* mlp_b1  = (const float*)d_in[8];
  const float* mlp_w2  = (const float*)d_in[9];
  const float* mlp_b2  = (const float*)d_in[10];
  const int* e_neg_src = (const int*)d_in[11];
  const int* e_neg_dst = (const int*)d_in[12];
  const int* e_con_src = (const int*)d_in[13];
  const int* e_con_dst = (const int*)d_in[14];
  const int* batch_var = (const int*)d_in[15];
  (void)n_in;

  const int V  = in_sizes[0] / D;
  const int C  = in_sizes[1] / D;
  const int L  = in_sizes[2] / (3 * D * D);
  const int EN = in_sizes[11];
  const int EC = in_sizes[13];
  const int B  = out_size;

  auto plan = [&](size_t esz) -> size_t {
    size_t o = 0;
    auto add = [&](size_t b) { o = (o + b + 255) & ~(size_t)255; };
    add((size_t)V * D * esz); add((size_t)C * D * esz);
    add((size_t)V * D * 2); add((size_t)V * D * 2); add((size_t)C * D * 2);
    add((size_t)V * 4); add((size_t)V * 4); add((size_t)V * 4); add((size_t)V * 4);
    add((size_t)C * 4); add((size_t)C * 4);
    add((size_t)L * 3 * 2 * D * 4);
    add((size_t)L * 3 * D * D * 2); add((size_t)L * 3 * D * D * 2);
    add((size_t)(V + 1) * 4); add((size_t)(C + 1) * 4); add((size_t)(V + 1) * 4);
    add((size_t)(2 * (size_t)V + C) * 4);
    add((size_t)EN * 4); add((size_t)EC * 4); add((size_t)EC * 4);
    add((size_t)EN * 8); add((size_t)EC * 8); add((size_t)EC * 8);
    add((size_t)3 * 1024 * 4);
    add((size_t)(B * D + B) * 4);
    return o;
  };

  if (plan(4) <= ws_size) {
    run_all<float>(x_var, x_con, W_src, W_dst, att_src, att_dst, bias,
                   mlp_w1, mlp_b1, mlp_w2, mlp_b2,
                   e_neg_src, e_neg_dst, e_con_src, e_con_dst, batch_var,
                   V, C, L, EN, EC, B, (char*)d_ws, (float*)d_out, stream);
  } else if (plan(2) <= ws_size) {
    run_all<bf16>(x_var, x_con, W_src, W_dst, att_src, att_dst, bias,
                  mlp_w1, mlp_b1, mlp_w2, mlp_b2,
                  e_neg_src, e_neg_dst, e_con_src, e_con_dst, batch_var,
                  V, C, L, EN, EC, B, (char*)d_ws, (float*)d_out, stream);
  } else {
    zero_kernel<<<(out_size + 63) / 64, 64, 0, stream>>>((float*)d_out, out_size);
  }
}

// Round 8
// 969.017 us; speedup vs baseline: 1.4777x; 1.0599x over previous
//
#include <hip/hip_runtime.h>
#include <hip/hip_bf16.h>
#include <cstdint>
#include <cstddef>

#define D 128

typedef __hip_bfloat16 bf16;
typedef __attribute__((ext_vector_type(8))) short short8v;   // 8 bf16 (4 VGPR)
typedef __attribute__((ext_vector_type(4))) float f32x4;     // MFMA 16x16 acc

// ---------- typed load/store helpers ----------
__device__ inline float ld1(const float* p) { return *p; }
__device__ inline float ld1(const bf16* p) { return __bfloat162float(*p); }
__device__ inline float2 ld2(const float* p) { return *(const float2*)p; }
__device__ inline float2 ld2(const bf16* p) {
  __hip_bfloat162 v = *(const __hip_bfloat162*)p;
  float2 r; r.x = __bfloat162float(v.x); r.y = __bfloat162float(v.y); return r;
}
__device__ inline void st2(float* p, float a, float b) {
  float2 v; v.x = a; v.y = b; *(float2*)p = v;
}
__device__ inline void st2(bf16* p, float a, float b) {
  __hip_bfloat162 v; v.x = __float2bfloat16(a); v.y = __float2bfloat16(b);
  *(__hip_bfloat162*)p = v;
}

// bf16 bit helpers (RNE)
__device__ inline short f2bf(float x) {
  uint32_t u = __builtin_bit_cast(uint32_t, x);
  uint32_t r = (u + 0x7FFFu + ((u >> 16) & 1u)) >> 16;
  return (short)(uint16_t)r;
}
__device__ inline float bf2f(short s) {
  uint32_t u = ((uint32_t)(uint16_t)s) << 16;
  return __builtin_bit_cast(float, u);
}

__device__ inline f32x4 mfma16(short8v a, short8v b, f32x4 c) {
  return __builtin_amdgcn_mfma_f32_16x16x32_bf16(a, b, c, 0, 0, 0);
}

__device__ __forceinline__ void load8(const float* p, float* v) {
  float4 a = *(const float4*)p;
  float4 b = *(const float4*)(p + 4);
  v[0] = a.x; v[1] = a.y; v[2] = a.z; v[3] = a.w;
  v[4] = b.x; v[5] = b.y; v[6] = b.z; v[7] = b.w;
}
__device__ __forceinline__ void load8(const bf16* p, float* v) {
  short8v s = *(const short8v*)p;
  #pragma unroll
  for (int j = 0; j < 8; ++j) v[j] = bf2f(s[j]);
}
__device__ __forceinline__ void split_store(short* Xh, short* Xl, int off, const float* v) {
  short8v h, l;
  #pragma unroll
  for (int j = 0; j < 8; ++j) {
    short hj = f2bf(v[j]);
    h[j] = hj;
    l[j] = f2bf(v[j] - bf2f(hj));
  }
  *(short8v*)&Xh[off] = h;
  *(short8v*)&Xl[off] = l;
}

// ---------- u[l,rel,side][k] = sum_j W[l,rel,k,j] * a[l,rel,j] ----------
__global__ void compute_u_kernel(const float* __restrict__ Wsrc, const float* __restrict__ Wdst,
                                 const float* __restrict__ asrc, const float* __restrict__ adst,
                                 float* __restrict__ u) {
  int lr = blockIdx.x;
  int side = blockIdx.y;
  int k = threadIdx.x;
  const float* W = (side == 0 ? Wsrc : Wdst) + ((size_t)lr * D + k) * D;
  const float* a = (side == 0 ? asrc : adst) + (size_t)lr * D;
  float s = 0.f;
  for (int j = 0; j < D; ++j) s += W[j] * a[j];
  u[((size_t)lr * 2 + side) * D + k] = s;
}

// ---------- W split: Wh/Wl bf16, transposed [col][k] ----------
__global__ void wsplit_kernel(const float* __restrict__ Wsrc,
                              short* __restrict__ WhT, short* __restrict__ WlT) {
  int lr = blockIdx.x;
  const float* W = Wsrc + (size_t)lr * D * D;
  short* wh = WhT + (size_t)lr * D * D;
  short* wl = WlT + (size_t)lr * D * D;
  for (int i = threadIdx.x; i < D * D; i += blockDim.x) {
    int k = i >> 7, c = i & 127;
    float w = W[i];
    short h = f2bf(w);
    short l = f2bf(w - bf2f(h));
    wh[c * D + k] = h;
    wl[c * D + k] = l;
  }
}

// ---------- CSR build ----------
__global__ void count_kernel(const int* __restrict__ dst, int* __restrict__ cnt, int E) {
  int i = blockIdx.x * blockDim.x + threadIdx.x;
  if (i < E) atomicAdd(&cnt[dst[i]], 1);
}

__global__ void count2_kernel(const int* __restrict__ csrc, const int* __restrict__ cdst,
                              int* __restrict__ cnt_bycon, int* __restrict__ cnt_byvar, int E) {
  int i = blockIdx.x * blockDim.x + threadIdx.x;
  if (i < E) {
    atomicAdd(&cnt_bycon[cdst[i]], 1);
    atomicAdd(&cnt_byvar[csrc[i]], 1);
  }
}

__global__ void bsum3_kernel(const int* __restrict__ c0, const int* __restrict__ c1,
                             const int* __restrict__ c2, int* __restrict__ bsums,
                             int n0, int n1, int n2, int pb0, int pb1, int pb2) {
  __shared__ int red[256];
  int y = blockIdx.y;
  const int* cnt = (y == 0) ? c0 : (y == 1) ? c1 : c2;
  int n  = (y == 0) ? n0 : (y == 1) ? n1 : n2;
  int pb = (y == 0) ? pb0 : (y == 1) ? pb1 : pb2;
  int b = blockIdx.x, t = threadIdx.x;
  int base = b * pb;
  if (base >= n) return;
  int end = base + pb; if (end > n) end = n;
  int s = 0;
  for (int i = base + t; i < end; i += 256) s += cnt[i];
  red[t] = s;
  __syncthreads();
  #pragma unroll
  for (int off = 128; off; off >>= 1) {
    if (t < off) red[t] += red[t + off];
    __syncthreads();
  }
  if (t == 0) bsums[y * 1024 + b] = red[0];
}

__global__ void bscan3_kernel(int* __restrict__ bsums,
                              int* __restrict__ t0, int* __restrict__ t1, int* __restrict__ t2) {
  __shared__ int sh[1024];
  int y = blockIdx.x, t = threadIdx.x;
  int* bs = bsums + y * 1024;
  int v = bs[t];
  sh[t] = v;
  __syncthreads();
  for (int off = 1; off < 1024; off <<= 1) {
    int u = (t >= off) ? sh[t - off] : 0;
    __syncthreads();
    sh[t] += u;
    __syncthreads();
  }
  bs[t] = sh[t] - v;
  if (t == 1023) {
    int* tot = (y == 0) ? t0 : (y == 1) ? t1 : t2;
    *tot = sh[1023];
  }
}

__global__ void scanfill3_kernel(const int* __restrict__ c0, const int* __restrict__ c1,
                                 const int* __restrict__ c2, const int* __restrict__ bsums,
                                 int* __restrict__ rp0, int* __restrict__ rp1, int* __restrict__ rp2,
                                 int* __restrict__ cu0, int* __restrict__ cu1, int* __restrict__ cu2,
                                 int n0, int n1, int n2, int pb0, int pb1, int pb2) {
  __shared__ int sh[256];
  int y = blockIdx.y;
  const int* cnt = (y == 0) ? c0 : (y == 1) ? c1 : c2;
  int* rowptr    = (y == 0) ? rp0 : (y == 1) ? rp1 : rp2;
  int* cursor    = (y == 0) ? cu0 : (y == 1) ? cu1 : cu2;
  int n  = (y == 0) ? n0 : (y == 1) ? n1 : n2;
  int pb = (y == 0) ? pb0 : (y == 1) ? pb1 : pb2;
  int b = blockIdx.x, t = threadIdx.x;
  int base = b * pb;
  if (base >= n) return;
  int end = base + pb; if (end > n) end = n;
  int run = bsums[y * 1024 + b];
  for (int tile = base; tile < end; tile += 256) {
    int i = tile + t;
    int c = (i < end) ? cnt[i] : 0;
    __syncthreads();
    sh[t] = c;
    __syncthreads();
    for (int off = 1; off < 256; off <<= 1) {
      int u = (t >= off) ? sh[t - off] : 0;
      __syncthreads();
      sh[t] += u;
      __syncthreads();
    }
    int excl = sh[t] - c;
    if (i < end) {
      rowptr[i] = run + excl;
      cursor[i] = run + excl;
    }
    run += sh[255];
  }
}

__global__ void fill_kernel(const int* __restrict__ dst, const int* __restrict__ src,
                            int* __restrict__ cursor, int* __restrict__ col, int E) {
  int i = blockIdx.x * blockDim.x + threadIdx.x;
  if (i < E) {
    int p = atomicAdd(&cursor[dst[i]], 1);
    col[p] = src[i];
  }
}

__global__ void fill2_kernel(const int* __restrict__ csrc, const int* __restrict__ cdst,
                             int* __restrict__ cur_bycon, int* __restrict__ cur_byvar,
                             int* __restrict__ col_bycon, int* __restrict__ col_byvar, int E) {
  int i = blockIdx.x * blockDim.x + threadIdx.x;
  if (i < E) {
    int s = csrc[i], d = cdst[i];
    int p = atomicAdd(&cur_bycon[d], 1);
    col_bycon[p] = s;
    int q = atomicAdd(&cur_byvar[s], 1);
    col_byvar[q] = d;
  }
}

// ---------- mmv3: 3 matmuls + fused attention matvecs ----------
// block = 512 thr (8 waves = 2 rowgrp x 4 colgrp); chunk = 32 rows x 128 cols.
// W-fragments register-resident; u-dots computed at staging time via 16-lane reduce.
template<typename Tin>
__global__ __launch_bounds__(512) void mmv3_kernel(
    const Tin* __restrict__ Xv, const Tin* __restrict__ Xc,
    const short* __restrict__ wh0, const short* __restrict__ wl0,
    const short* __restrict__ wh1, const short* __restrict__ wl1,
    const short* __restrict__ wh2, const short* __restrict__ wl2,
    bf16* __restrict__ H0, bf16* __restrict__ H1, bf16* __restrict__ H2,
    const float* __restrict__ uv0, const float* __restrict__ uv1,
    const float* __restrict__ uv2, const float* __restrict__ uv3,
    const float* __restrict__ uc0, const float* __restrict__ uc1,
    float* __restrict__ es0, float* __restrict__ ed0,
    float* __restrict__ es1, float* __restrict__ ed2,
    float* __restrict__ es2, float* __restrict__ ed1,
    int V, int C, int b0, int b1, int b2) {
  __shared__ short sbuf[2][2][32 * 136];   // [buf][h/l][row*136+k]
  int bid = blockIdx.x;
  const Tin* X; const short* wh; const short* wl; bf16* H;
  int nrows, lb, nblk, ndots;
  const float *U0, *U1, *U2, *U3;
  float *O0, *O1, *O2, *O3;
  if (bid < b0) {
    X = Xv; wh = wh0; wl = wl0; H = H0; nrows = V; lb = bid; nblk = b0;
    ndots = 4; U0 = uv0; U1 = uv1; U2 = uv2; U3 = uv3;
    O0 = es0; O1 = ed0; O2 = es1; O3 = ed2;
  } else if (bid < b1) {
    X = Xv; wh = wh1; wl = wl1; H = H1; nrows = V; lb = bid - b0; nblk = b1 - b0;
    ndots = 0; U0 = U1 = U2 = U3 = nullptr; O0 = O1 = O2 = O3 = nullptr;
  } else {
    X = Xc; wh = wh2; wl = wl2; H = H2; nrows = C; lb = bid - b1; nblk = b2 - b1;
    ndots = 2; U0 = uc0; U1 = uc1; U2 = U3 = nullptr;
    O0 = es2; O1 = ed1; O2 = O3 = nullptr;
  }
  int nchunks = nrows >> 5;
  if (lb >= nchunks) return;

  int tid = threadIdx.x;
  int wv = tid >> 6, lane = tid & 63;
  int c15 = lane & 15, q = lane >> 4;
  int rowgrp = wv >> 2, colgrp = wv & 3;

  // one-time W fragment load -> registers
  short8v Bh[2][4], Bl[2][4];
  #pragma unroll
  for (int t = 0; t < 2; ++t) {
    #pragma unroll
    for (int ks = 0; ks < 4; ++ks) {
      int o = (colgrp * 32 + t * 16 + c15) * D + ks * 32 + q * 8;
      Bh[t][ks] = *(const short8v*)&wh[o];
      Bl[t][ks] = *(const short8v*)&wl[o];
    }
  }

  int srow = tid >> 4;            // 0..31
  int scol = (tid & 15) * 8;      // 0..120
  int soff = srow * 136 + scol;

  // one-time u-vector register load (8 elems per thread at scol)
  float u0r[8], u1r[8], u2r[8], u3r[8];
  if (ndots) {
    load8(U0 + scol, u0r);
    load8(U1 + scol, u1r);
    if (ndots == 4) { load8(U2 + scol, u2r); load8(U3 + scol, u3r); }
  }

  auto do_dots = [&](const float* v, int gr) {
    if (!ndots) return;
    float p0 = 0.f, p1 = 0.f, p2 = 0.f, p3 = 0.f;
    #pragma unroll
    for (int j = 0; j < 8; ++j) { p0 += v[j] * u0r[j]; p1 += v[j] * u1r[j]; }
    if (ndots == 4) {
      #pragma unroll
      for (int j = 0; j < 8; ++j) { p2 += v[j] * u2r[j]; p3 += v[j] * u3r[j]; }
    }
    #pragma unroll
    for (int off = 1; off < 16; off <<= 1) {
      p0 += __shfl_xor(p0, off);
      p1 += __shfl_xor(p1, off);
      if (ndots == 4) { p2 += __shfl_xor(p2, off); p3 += __shfl_xor(p3, off); }
    }
    if ((tid & 15) == 0) {
      O0[gr] = p0; O1[gr] = p1;
      if (ndots == 4) { O2[gr] = p2; O3[gr] = p3; }
    }
  };

  {  // prologue: stage first chunk into buf 0
    float v[8];
    int gr = lb * 32 + srow; if (gr >= nrows) gr = nrows - 1;
    load8(X + (size_t)gr * D + scol, v);
    do_dots(v, gr);
    split_store(&sbuf[0][0][0], &sbuf[0][1][0], soff, v);
  }
  __syncthreads();

  int aoff = (rowgrp * 16 + c15) * 136 + q * 8;
  int cur = 0;
  for (int chunk = lb; chunk < nchunks; chunk += nblk) {
    int nxt = chunk + nblk;
    bool have = nxt < nchunks;
    float v[8];
    if (have) {
      int gr = nxt * 32 + srow; if (gr >= nrows) gr = nrows - 1;
      load8(X + (size_t)gr * D + scol, v);
      do_dots(v, gr);
    }
    const short* Ah = &sbuf[cur][0][aoff];
    const short* Al = &sbuf[cur][1][aoff];
    f32x4 a0 = (f32x4){0.f, 0.f, 0.f, 0.f};
    f32x4 a1 = (f32x4){0.f, 0.f, 0.f, 0.f};
    #pragma unroll
    for (int ks = 0; ks < 4; ++ks) {
      short8v xh = *(const short8v*)(Ah + ks * 32);
      short8v xl = *(const short8v*)(Al + ks * 32);
      a0 = mfma16(Bh[0][ks], xh, a0);
      a1 = mfma16(Bh[1][ks], xh, a1);
      a0 = mfma16(Bl[0][ks], xh, a0);
      a1 = mfma16(Bl[1][ks], xh, a1);
      a0 = mfma16(Bh[0][ks], xl, a0);
      a1 = mfma16(Bh[1][ks], xl, a1);
    }
    int gr = chunk * 32 + rowgrp * 16 + c15;
    if (gr < nrows) {
      short4 o0, o1;
      o0.x = f2bf(a0[0]); o0.y = f2bf(a0[1]); o0.z = f2bf(a0[2]); o0.w = f2bf(a0[3]);
      o1.x = f2bf(a1[0]); o1.y = f2bf(a1[1]); o1.z = f2bf(a1[2]); o1.w = f2bf(a1[3]);
      size_t base = (size_t)gr * D + colgrp * 32 + q * 4;
      *(short4*)((short*)H + base) = o0;
      *(short4*)((short*)H + base + 16) = o1;
    }
    if (have) split_store(&sbuf[cur ^ 1][0][0], &sbuf[cur ^ 1][1][0], soff, v);
    __syncthreads();
    cur ^= 1;
  }
}

// ---------- alpha pass: per-dst softmax -> CSR-ordered (src, alpha) pairs ----------
__device__ __forceinline__ void alpha_rel(const int* __restrict__ rp, const int* __restrict__ col,
                                          const float* __restrict__ es, float edst,
                                          int gw, int lane, int2* __restrict__ edata) {
  int p0 = rp[gw];
  int deg = rp[gw + 1] - p0;
  if (deg <= 0) return;
  if (deg <= 64) {
    int s = 0; float e = -3.0e38f;
    if (lane < deg) {
      s = col[p0 + lane];
      float t = es[s] + edst;
      e = t > 0.f ? t : 0.2f * t;
    }
    float m = e;
    #pragma unroll
    for (int off = 32; off; off >>= 1) m = fmaxf(m, __shfl_xor(m, off));
    float ex = (lane < deg) ? __expf(e - m) : 0.f;
    float den = ex;
    #pragma unroll
    for (int off = 32; off; off >>= 1) den += __shfl_xor(den, off);
    float al = ex / (den + 1e-16f);
    if (lane < deg) {
      int2 v; v.x = s; v.y = __builtin_bit_cast(int, al);
      edata[p0 + lane] = v;
    }
  } else {
    float m = -3.0e38f;
    for (int j = lane; j < deg; j += 64) {
      int s = col[p0 + j];
      float t = es[s] + edst;
      t = t > 0.f ? t : 0.2f * t;
      m = fmaxf(m, t);
    }
    #pragma unroll
    for (int off = 32; off; off >>= 1) m = fmaxf(m, __shfl_xor(m, off));
    float den = 0.f;
    for (int j = lane; j < deg; j += 64) {
      int s = col[p0 + j];
      float t = es[s] + edst;
      t = t > 0.f ? t : 0.2f * t;
      den += __expf(t - m);
    }
    #pragma unroll
    for (int off = 32; off; off >>= 1) den += __shfl_xor(den, off);
    float inv = 1.f / (den + 1e-16f);
    for (int j = lane; j < deg; j += 64) {
      int s = col[p0 + j];
      float t = es[s] + edst;
      t = t > 0.f ? t : 0.2f * t;
      int2 v; v.x = s; v.y = __builtin_bit_cast(int, __expf(t - m) * inv);
      edata[p0 + j] = v;
    }
  }
}

__global__ void alpha_all_kernel(const int* __restrict__ rp0, const int* __restrict__ col0,
                                 const float* __restrict__ es0, const float* __restrict__ ed0,
                                 int2* __restrict__ eda0,
                                 const int* __restrict__ rp2, const int* __restrict__ col2,
                                 const float* __restrict__ es2, const float* __restrict__ ed2,
                                 int2* __restrict__ eda2,
                                 const int* __restrict__ rp1, const int* __restrict__ col1,
                                 const float* __restrict__ es1, const float* __restrict__ ed1,
                                 int2* __restrict__ eda1,
                                 int V, int C) {
  int gw = (int)(((size_t)blockIdx.x * blockDim.x + threadIdx.x) >> 6);
  int lane = threadIdx.x & 63;
  if (gw < V) {
    alpha_rel(rp0, col0, es0, ed0[gw], gw, lane, eda0);
    alpha_rel(rp2, col2, es2, ed2[gw], gw, lane, eda2);
  } else if (gw < V + C) {
    int g = gw - V;
    alpha_rel(rp1, col1, es1, ed1[g], g, lane, eda1);
  }
}

// ---------- gather pass ----------
__device__ __forceinline__ void agg_rel(const int2* __restrict__ edata, int p0, int p1,
                                        const bf16* __restrict__ hs, int l2,
                                        float& a0, float& a1) {
  int q = p0;
  while (q + 4 <= p1) {
    int2 e0 = edata[q], e1 = edata[q + 1], e2 = edata[q + 2], e3 = edata[q + 3];
    int s0 = __builtin_amdgcn_readfirstlane(e0.x);
    int s1 = __builtin_amdgcn_readfirstlane(e1.x);
    int s2 = __builtin_amdgcn_readfirstlane(e2.x);
    int s3 = __builtin_amdgcn_readfirstlane(e3.x);
    float w0 = __builtin_bit_cast(float, __builtin_amdgcn_readfirstlane(e0.y));
    float w1 = __builtin_bit_cast(float, __builtin_amdgcn_readfirstlane(e1.y));
    float w2 = __builtin_bit_cast(float, __builtin_amdgcn_readfirstlane(e2.y));
    float w3 = __builtin_bit_cast(float, __builtin_amdgcn_readfirstlane(e3.y));
    float2 h0 = ld2(&hs[(size_t)s0 * D + l2]);
    float2 h1 = ld2(&hs[(size_t)s1 * D + l2]);
    float2 h2 = ld2(&hs[(size_t)s2 * D + l2]);
    float2 h3 = ld2(&hs[(size_t)s3 * D + l2]);
    a0 += w0 * h0.x + w1 * h1.x + w2 * h2.x + w3 * h3.x;
    a1 += w0 * h0.y + w1 * h1.y + w2 * h2.y + w3 * h3.y;
    q += 4;
  }
  while (q < p1) {
    int2 e = edata[q++];
    int s = __builtin_amdgcn_readfirstlane(e.x);
    float w = __builtin_bit_cast(float, __builtin_amdgcn_readfirstlane(e.y));
    float2 h = ld2(&hs[(size_t)s * D + l2]);
    a0 += w * h.x;
    a1 += w * h.y;
  }
}

__global__ void agg_all_kernel(const int* __restrict__ rp0, const int2* __restrict__ eda0,
                               const bf16* __restrict__ hsv0, const float* __restrict__ b0,
                               const int* __restrict__ rp2, const int2* __restrict__ eda2,
                               const bf16* __restrict__ hsc, const float* __restrict__ b2,
                               const int* __restrict__ rp1, const int2* __restrict__ eda1,
                               const bf16* __restrict__ hsv1, const float* __restrict__ b1,
                               bf16* __restrict__ xv_out, bf16* __restrict__ xc_out, int V, int C) {
  int gw = (int)(((size_t)blockIdx.x * blockDim.x + threadIdx.x) >> 6);
  int lane = threadIdx.x & 63;
  int l2 = 2 * lane;
  if (gw < V) {
    float a0 = 0.f, a1 = 0.f;
    agg_rel(eda0, rp0[gw], rp0[gw + 1], hsv0, l2, a0, a1);
    agg_rel(eda2, rp2[gw], rp2[gw + 1], hsc, l2, a0, a1);
    float v0 = a0 + b0[l2] + b2[l2];
    float v1 = a1 + b0[l2 + 1] + b2[l2 + 1];
    st2(&xv_out[(size_t)gw * D + l2], v0 > 0.f ? v0 : 0.f, v1 > 0.f ? v1 : 0.f);
  } else if (gw < V + C) {
    int g = gw - V;
    float a0 = 0.f, a1 = 0.f;
    agg_rel(eda1, rp1[g], rp1[g + 1], hsv1, l2, a0, a1);
    float v0 = a0 + b1[l2];
    float v1 = a1 + b1[l2 + 1];
    st2(&xc_out[(size_t)g * D + l2], v0 > 0.f ? v0 : 0.f, v1 > 0.f ? v1 : 0.f);
  }
}

// ---------- pooling over sorted batch ids ----------
__global__ void pool_kernel(const bf16* __restrict__ xv, const int* __restrict__ batch,
                            float* __restrict__ pooled, float* __restrict__ cntf,
                            int rowsPerBlock, int V) {
  int j = threadIdx.x;
  int r0 = blockIdx.x * rowsPerBlock;
  if (r0 >= V) return;
  int rend = r0 + rowsPerBlock; if (rend > V) rend = V;
  int cur = batch[r0];
  float s = 0.f;
  int run = 0;
  for (int r = r0; r < rend; ++r) {
    int b = batch[r];
    if (b != cur) {
      atomicAdd(&pooled[(size_t)cur * D + j], s);
      if (j == 0) atomicAdd(&cntf[cur], (float)run);
      s = 0.f; run = 0; cur = b;
    }
    s += ld1(&xv[(size_t)r * D + j]);
    run++;
  }
  atomicAdd(&pooled[(size_t)cur * D + j], s);
  if (j == 0) atomicAdd(&cntf[cur], (float)run);
}

// ---------- final MLP ----------
__global__ void mlp_kernel(const float* __restrict__ pooled, const float* __restrict__ cntf,
                           const float* __restrict__ w1, const float* __restrict__ b1,
                           const float* __restrict__ w2, const float* __restrict__ b2,
                           float* __restrict__ out, int B) {
  __shared__ float P[32 * D];
  __shared__ float Hs[32 * D];
  int tid = threadIdx.x;
  if (B > 32) return;
  for (int i = tid; i < B * D; i += 256) {
    int r = i >> 7;
    P[i] = pooled[i] / fmaxf(cntf[r], 1.0f);
  }
  __syncthreads();
  for (int i = tid; i < B * D; i += 256) {
    int r = i >> 7, j = i & 127;
    float s = b1[j];
    for (int k = 0; k < D; ++k) s += P[r * D + k] * w1[k * D + j];
    Hs[i] = s > 0.f ? s : 0.f;
  }
  __syncthreads();
  if (tid < B) {
    float s = b2[0];
    for (int j = 0; j < D; ++j) s += Hs[tid * D + j] * w2[j];
    out[tid] = s;
  }
}

__global__ void zero_kernel(float* __restrict__ o, int n) {
  int i = blockIdx.x * blockDim.x + threadIdx.x;
  if (i < n) o[i] = 0.f;
}

// ---------- full pipeline (features stored bf16, compute fp32) ----------
static void run_all(const float* x_var, const float* x_con,
                    const float* W_src, const float* W_dst,
                    const float* att_src, const float* att_dst, const float* bias,
                    const float* mlp_w1, const float* mlp_b1,
                    const float* mlp_w2, const float* mlp_b2,
                    const int* e_neg_src, const int* e_neg_dst,
                    const int* e_con_src, const int* e_con_dst, const int* batch_var,
                    int V, int C, int L, int EN, int EC, int B,
                    char* ws, float* out, hipStream_t stream) {
  size_t off = 0;
  auto alloc = [&](size_t bytes) -> char* {
    char* p = ws + off;
    off = (off + bytes + 255) & ~(size_t)255;
    return p;
  };
  bf16* xv  = (bf16*)alloc((size_t)V * D * 2);
  bf16* xc  = (bf16*)alloc((size_t)C * D * 2);
  bf16* hsv0 = (bf16*)alloc((size_t)V * D * 2);
  bf16* hsv1 = (bf16*)alloc((size_t)V * D * 2);
  bf16* hsc  = (bf16*)alloc((size_t)C * D * 2);
  float* es0 = (float*)alloc((size_t)V * 4);
  float* ed0 = (float*)alloc((size_t)V * 4);
  float* es1 = (float*)alloc((size_t)V * 4);
  float* ed2 = (float*)alloc((size_t)V * 4);
  float* es2 = (float*)alloc((size_t)C * 4);
  float* ed1 = (float*)alloc((size_t)C * 4);
  float* u   = (float*)alloc((size_t)L * 3 * 2 * D * 4);
  short* whT = (short*)alloc((size_t)L * 3 * D * D * 2);
  short* wlT = (short*)alloc((size_t)L * 3 * D * D * 2);
  int* rp0  = (int*)alloc((size_t)(V + 1) * 4);
  int* rp1  = (int*)alloc((size_t)(C + 1) * 4);
  int* rp2  = (int*)alloc((size_t)(V + 1) * 4);
  int* curs = (int*)alloc((size_t)(2 * (size_t)V + C) * 4);
  int* cur0 = curs, *cur1 = curs + V, *cur2 = curs + V + C;
  int* col0 = (int*)alloc((size_t)EN * 4);
  int* col1 = (int*)alloc((size_t)EC * 4);
  int* col2 = (int*)alloc((size_t)EC * 4);
  int2* eda0 = (int2*)alloc((size_t)EN * 8);
  int2* eda1 = (int2*)alloc((size_t)EC * 8);
  int2* eda2 = (int2*)alloc((size_t)EC * 8);
  int* bsums = (int*)alloc((size_t)3 * 1024 * 4);
  float* pooled = (float*)alloc((size_t)(B * D + B) * 4);
  float* cntf = pooled + (size_t)B * D;

  hipMemsetAsync(curs, 0, (size_t)(2 * (size_t)V + C) * 4, stream);
  hipMemsetAsync(bsums, 0, (size_t)3 * 1024 * 4, stream);
  hipMemsetAsync(pooled, 0, (size_t)(B * D + B) * 4, stream);

  compute_u_kernel<<<dim3(L * 3, 2), D, 0, stream>>>(W_src, W_dst, att_src, att_dst, u);
  wsplit_kernel<<<L * 3, 256, 0, stream>>>(W_src, whT, wlT);

  const int tb = 256;
  count_kernel<<<(EN + tb - 1) / tb, tb, 0, stream>>>(e_neg_dst, cur0, EN);
  count2_kernel<<<(EC + tb - 1) / tb, tb, 0, stream>>>(e_con_src, e_con_dst, cur1, cur2, EC);

  auto pbof = [](int n) {
    int pb = ((n + 1023) / 1024 + 255) & ~255;
    return pb < 256 ? 256 : pb;
  };
  int pb0 = pbof(V), pb1 = pbof(C), pb2 = pbof(V);
  int nb0 = (V + pb0 - 1) / pb0, nb1 = (C + pb1 - 1) / pb1, nb2 = (V + pb2 - 1) / pb2;
  int nbmax = nb0 > nb1 ? nb0 : nb1; if (nb2 > nbmax) nbmax = nb2;
  bsum3_kernel<<<dim3(nbmax, 3), 256, 0, stream>>>(cur0, cur1, cur2, bsums, V, C, V, pb0, pb1, pb2);
  bscan3_kernel<<<3, 1024, 0, stream>>>(bsums, rp0 + V, rp1 + C, rp2 + V);
  scanfill3_kernel<<<dim3(nbmax, 3), 256, 0, stream>>>(cur0, cur1, cur2, bsums,
                                                       rp0, rp1, rp2, cur0, cur1, cur2,
                                                       V, C, V, pb0, pb1, pb2);

  fill_kernel<<<(EN + tb - 1) / tb, tb, 0, stream>>>(e_neg_dst, e_neg_src, cur0, col0, EN);
  fill2_kernel<<<(EC + tb - 1) / tb, tb, 0, stream>>>(e_con_src, e_con_dst, cur1, cur2, col1, col2, EC);

  auto U  = [&](int l, int rel, int side) { return u + (((size_t)l * 3 + rel) * 2 + side) * D; };
  auto Wh = [&](int l, int rel) { return whT + ((size_t)l * 3 + rel) * D * D; };
  auto Wl = [&](int l, int rel) { return wlT + ((size_t)l * 3 + rel) * D * D; };
  auto Bp = [&](int l, int rel) { return bias + ((size_t)l * 3 + rel) * D; };

  int gwaves = (V + C + 3) / 4;
  const int MB0 = 512, MB1 = 1024, MB2 = 1280;

  for (int l = 0; l < L; ++l) {
    if (l == 0) {
      mmv3_kernel<float><<<MB2, 512, 0, stream>>>(
          x_var, x_con, Wh(l,0), Wl(l,0), Wh(l,1), Wl(l,1), Wh(l,2), Wl(l,2),
          hsv0, hsv1, hsc,
          U(l,0,0), U(l,0,1), U(l,1,0), U(l,2,1), U(l,2,0), U(l,1,1),
          es0, ed0, es1, ed2, es2, ed1, V, C, MB0, MB1, MB2);
    } else {
      mmv3_kernel<bf16><<<MB2, 512, 0, stream>>>(
          xv, xc, Wh(l,0), Wl(l,0), Wh(l,1), Wl(l,1), Wh(l,2), Wl(l,2),
          hsv0, hsv1, hsc,
          U(l,0,0), U(l,0,1), U(l,1,0), U(l,2,1), U(l,2,0), U(l,1,1),
          es0, ed0, es1, ed2, es2, ed1, V, C, MB0, MB1, MB2);
    }
    alpha_all_kernel<<<gwaves, 256, 0, stream>>>(
        rp0, col0, es0, ed0, eda0,
        rp2, col2, es2, ed2, eda2,
        rp1, col1, es1, ed1, eda1, V, C);
    agg_all_kernel<<<gwaves, 256, 0, stream>>>(
        rp0, eda0, hsv0, Bp(l,0),
        rp2, eda2, hsc,  Bp(l,2),
        rp1, eda1, hsv1, Bp(l,1),
        xv, xc, V, C);
  }

  pool_kernel<<<(V + 127) / 128, 128, 0, stream>>>(xv, batch_var, pooled, cntf, 128, V);
  mlp_kernel<<<1, 256, 0, stream>>>(pooled, cntf, mlp_w1, mlp_b1, mlp_w2, mlp_b2, out, B);
}

extern "C" void kernel_launch(void* const* d_in, const int* in_sizes, int n_in,
                              void* d_out, int out_size, void* d_ws, size_t ws_size,
                              hipStream_t stream) {
  const float* x_var   = (const float*)d_in[0];
  const float* x_con   = (const float*)d_in[1];
  const float* W_src   = (const float*)d_in[2];
  const float* W_dst   = (const float*)d_in[3];
  const float* att_src = (const float*)d_in[4];
  const float* att_dst = (const float*)d_in[5];
  const float* bias    = (const float*)d_in[6];
  const float* mlp_w1  = (const float*)d_in[7];
  const float* mlp_b1  = (const float*)d_in[8];
  const float* mlp_w2  = (const float*)d_in[9];
  const float* mlp_b2  = (const float*)d_in[10];
  const int* e_neg_src = (const int*)d_in[11];
  const int* e_neg_dst = (const int*)d_in[12];
  const int* e_con_src = (const int*)d_in[13];
  const int* e_con_dst = (const int*)d_in[14];
  const int* batch_var = (const int*)d_in[15];
  (void)n_in;

  const int V  = in_sizes[0] / D;
  const int C  = in_sizes[1] / D;
  const int L  = in_sizes[2] / (3 * D * D);
  const int EN = in_sizes[11];
  const int EC = in_sizes[13];
  const int B  = out_size;

  auto plan = [&]() -> size_t {
    size_t o = 0;
    auto add = [&](size_t b) { o = (o + b + 255) & ~(size_t)255; };
    add((size_t)V * D * 2); add((size_t)C * D * 2);
    add((size_t)V * D * 2); add((size_t)V * D * 2); add((size_t)C * D * 2);
    add((size_t)V * 4); add((size_t)V * 4); add((size_t)V * 4); add((size_t)V * 4);
    add((size_t)C * 4); add((size_t)C * 4);
    add((size_t)L * 3 * 2 * D * 4);
    add((size_t)L * 3 * D * D * 2); add((size_t)L * 3 * D * D * 2);
    add((size_t)(V + 1) * 4); add((size_t)(C + 1) * 4); add((size_t)(V + 1) * 4);
    add((size_t)(2 * (size_t)V + C) * 4);
    add((size_t)EN * 4); add((size_t)EC * 4); add((size_t)EC * 4);
    add((size_t)EN * 8); add((size_t)EC * 8); add((size_t)EC * 8);
    add((size_t)3 * 1024 * 4);
    add((size_t)(B * D + B) * 4);
    return o;
  };

  if (plan() <= ws_size) {
    run_all(x_var, x_con, W_src, W_dst, att_src, att_dst, bias,
            mlp_w1, mlp_b1, mlp_w2, mlp_b2,
            e_neg_src, e_neg_dst, e_con_src, e_con_dst, batch_var,
            V, C, L, EN, EC, B, (char*)d_ws, (float*)d_out, stream);
  } else {
    zero_kernel<<<(out_size + 63) / 64, 64, 0, stream>>>((float*)d_out, out_size);
  }
}